// Round 11
// baseline (243.316 us; speedup 1.0000x reference)
//
#include <hip/hip_runtime.h>

typedef __bf16 bf16x8 __attribute__((ext_vector_type(8)));
typedef float f32x4 __attribute__((ext_vector_type(4)));

#define SL2E 0.18033688011112042f  // log2(e)/8, folded into Q at gemm_qkv epilogue

__device__ __forceinline__ unsigned short f2bf(float f) {
  union { float f; unsigned u; } v; v.f = f;
  unsigned r = v.u + 0x7fffu + ((v.u >> 16) & 1u);
  return (unsigned short)(r >> 16);
}

__device__ __forceinline__ float fast_exp2(float x) {
#if __has_builtin(__builtin_amdgcn_exp2f)
  return __builtin_amdgcn_exp2f(x);
#else
  return exp2f(x);
#endif
}

__device__ __forceinline__ unsigned pack_bf2(float lo, float hi) {
  union { float f; unsigned u; } a, b;
  a.f = lo; b.f = hi;
#if __has_builtin(__builtin_amdgcn_perm)
  return __builtin_amdgcn_perm(b.u + 0x7fffu, a.u + 0x7fffu, 0x07060302u);
#else
  return ((b.u + 0x7fffu) & 0xffff0000u) | ((a.u + 0x7fffu) >> 16);
#endif
}

// async global->LDS, 16B/lane; HW dest = readfirstlane(lds base) + lane*16
__device__ __forceinline__ void gload16(const unsigned short* g, unsigned short* l) {
  __builtin_amdgcn_global_load_lds(
      (const __attribute__((address_space(1))) unsigned int*)g,
      (__attribute__((address_space(3))) unsigned int*)l, 16, 0, 0);
}

// swizzled chunk address (shorts): row R (64-short rows), colgroup cg of 8 shorts
#define SWZ(r, cg) ((((r) * 8) + ((cg) ^ ((r) & 7))) * 8)

// ---------------- fused fp32 -> bf16 conversion (x, w_qkv, w_out) ----------------
__global__ __launch_bounds__(256) void f32_to_bf16_all(
    const float* __restrict__ x, const float* __restrict__ wq, const float* __restrict__ wo,
    unsigned short* __restrict__ xb, unsigned short* __restrict__ wqb, unsigned short* __restrict__ wob) {
  int i = blockIdx.x * 256 + threadIdx.x;  // quad index
  const float* src; unsigned short* dst; int off;
  if (i < 2097152) { src = x; dst = xb; off = i; }
  else if (i < 2883584) { src = wq; dst = wqb; off = i - 2097152; }
  else if (i < 3145728) { src = wo; dst = wob; off = i - 2883584; }
  else return;
  float4 v = ((const float4*)src)[off];
  ushort4 o;
  o.x = f2bf(v.x); o.y = f2bf(v.y); o.z = f2bf(v.z); o.w = f2bf(v.w);
  ((ushort4*)dst)[off] = o;
}

// ============ GEMM1: 128x192 block, BK=64, 4 waves of 64x96 (2M x 2N) ============
// r8's wave-tile efficiency (64x96, DS bytes/MFLOP 34.3 - measured 1.13x win) +
// cross-block TLP: LDS 80KB (2 dbuf x (A 16KB + B 24KB)) -> 2 independent blocks/CU
// (two barrier domains; one block's waves fill the other's stage/barrier stalls,
// the m114 mechanism that r3's 5-block config had and r8's 1-block config lost).
// 2-phase counted-vmcnt schedule (r6/r8-verified): stage next tile -> buf^1,
// vmcnt(10) retires exactly the current tile's 10 loads/wave, barrier, compute.

template <bool SWAP>
__device__ __forceinline__ void tile_compute_6x4(
    const unsigned short* As_, const unsigned short* Bs_,
    int l15, int quad, int wm, int wn, f32x4* acc) {
#pragma unroll
  for (int kk = 0; kk < 2; ++kk) {
    int cg = kk * 4 + quad;
    bf16x8 af[4], bfr[6];
#pragma unroll
    for (int i = 0; i < 4; ++i) af[i] = *(const bf16x8*)(As_ + SWZ(wm + i * 16 + l15, cg));
#pragma unroll
    for (int j = 0; j < 6; ++j) bfr[j] = *(const bf16x8*)(Bs_ + SWZ(wn + j * 16 + l15, cg));
    if constexpr (SWAP) {
#pragma unroll
      for (int j = 0; j < 6; ++j)
#pragma unroll
        for (int i = 0; i < 4; ++i)
          acc[j * 4 + i] = __builtin_amdgcn_mfma_f32_16x16x32_bf16(bfr[j], af[i], acc[j * 4 + i], 0, 0, 0);
    } else {
#pragma unroll
      for (int i = 0; i < 4; ++i)
#pragma unroll
        for (int j = 0; j < 6; ++j)
          acc[i * 6 + j] = __builtin_amdgcn_mfma_f32_16x16x32_bf16(af[i], bfr[j], acc[i * 6 + j], 0, 0, 0);
    }
  }
}

template <bool SWAP>
__device__ __forceinline__ void mainloop_128x192(
    const unsigned short* const srcp[10], const int ldso[10],
    unsigned short* lds0, unsigned short* lds1,
    int l15, int quad, int wm, int wn, f32x4* acc) {
  // prologue: stage tile 0 -> buf0 (10 loads in flight per wave)
#pragma unroll
  for (int i = 0; i < 10; ++i) gload16(srcp[i], lds0 + ldso[i]);
#pragma unroll 1
  for (int t2 = 0; t2 < 16; t2 += 2) {
    // ---- body A: stage t2+1 -> buf1; compute buf0 ----
#pragma unroll
    for (int i = 0; i < 10; ++i) gload16(srcp[i] + (t2 + 1) * 64, lds1 + ldso[i]);
    asm volatile("s_waitcnt vmcnt(10)" ::: "memory");  // tile t2 landed; t2+1 in flight
    __builtin_amdgcn_s_barrier();
    __builtin_amdgcn_sched_barrier(0);
    tile_compute_6x4<SWAP>(lds0, lds0 + 8192, l15, quad, wm, wn, acc);
    __builtin_amdgcn_s_barrier();   // all waves done reading buf0 -> re-stageable
    // ---- body B: stage t2+2 -> buf0; compute buf1 ----
    if (t2 < 14) {
#pragma unroll
      for (int i = 0; i < 10; ++i) gload16(srcp[i] + (t2 + 2) * 64, lds0 + ldso[i]);
      asm volatile("s_waitcnt vmcnt(10)" ::: "memory");
    } else {
      asm volatile("s_waitcnt vmcnt(0)" ::: "memory");  // last tile: nothing younger
    }
    __builtin_amdgcn_s_barrier();
    __builtin_amdgcn_sched_barrier(0);
    tile_compute_6x4<SWAP>(lds1, lds1 + 8192, l15, quad, wm, wn, acc);
    __builtin_amdgcn_s_barrier();
  }
}

// ---------------- GEMM1: qkv = x @ w_qkv^T + b, scatter to Q/K/Vt ----------------
__global__ __launch_bounds__(256, 2) void gemm_qkv(
    const unsigned short* __restrict__ A,
    const unsigned short* __restrict__ Bt,
    const float* __restrict__ bias,
    unsigned short* __restrict__ Qb,
    unsigned short* __restrict__ Kb,
    unsigned short* __restrict__ Vtb) {
  const int K = 1024;
  // buf layout (shorts): [0,8192) = A tile 128x64; [8192, 20480) = B tile 192x64
  __shared__ unsigned short SMEM[2][20480];
  int tid = threadIdx.x;
  int w = tid >> 6, lane = tid & 63, l15 = lane & 15, quad = lane >> 4;
  int m0 = blockIdx.x * 128, n0 = blockIdx.y * 192;
  int wm = (w & 1) * 64, wn = (w >> 1) * 96;
  int b = m0 >> 12;

  // staging slots: 40 chunks (A rows q*8.., q<16; B rows (q-16)*8..), 10 per wave
  int rlane = lane >> 3;
  int cs = ((lane & 7) ^ rlane) * 8;  // inverse-swizzle source colgroup
  const unsigned short* srcp[10];
  int ldso[10];
#pragma unroll
  for (int i = 0; i < 10; ++i) {
    int q = w * 10 + i;
    if (q < 16) { srcp[i] = A + (m0 + q * 8 + rlane) * K + cs; ldso[i] = q * 512; }
    else { srcp[i] = Bt + (n0 + (q - 16) * 8 + rlane) * K + cs; ldso[i] = 8192 + (q - 16) * 512; }
  }

  f32x4 acc[24] = {};

  bool pureV = (n0 >= 2048);
  bool mixed = (n0 < 2048) && (n0 + 192 > 2048);   // n0 == 1920 only

  if (!pureV && !mixed) {
    // ---- Q/K blocks (incl. Q/K straddle at n0=960): swapped operands ----
    // lane owns (s = l15, 4 consecutive d on quad*4+reg)
    mainloop_128x192<true>(srcp, ldso, &SMEM[0][0], &SMEM[1][0], l15, quad, wm, wn, acc);
    int s_base = (m0 & 4095) + wm;
#pragma unroll
    for (int j = 0; j < 6; ++j) {
      int ng = n0 + wn + j * 16;                   // 16-aligned, never crosses 1024
      int t = ng >> 10;                            // 0=Q, 1=K (per-j)
      unsigned short* dst = t ? Kb : Qb;
      float sc = t ? 1.0f : SL2E;
      int h = (ng >> 6) & 15;
      int d0 = (ng & 63) + quad * 4;
      float4 bv = *(const float4*)(bias + ng + quad * 4);
      int head_base = (b * 16 + h) * 4096 * 64;
#pragma unroll
      for (int i = 0; i < 4; ++i) {
        int s = s_base + i * 16 + l15;
        f32x4 a = acc[j * 4 + i];
        ushort4 pk;
        pk.x = f2bf((a[0] + bv.x) * sc);
        pk.y = f2bf((a[1] + bv.y) * sc);
        pk.z = f2bf((a[2] + bv.z) * sc);
        pk.w = f2bf((a[3] + bv.w) * sc);
        *(ushort4*)(dst + head_base + s * 64 + d0) = pk;
      }
    }
  } else if (pureV) {
    // ---- pure V blocks: original orientation, lane owns (d=l15, 4 consecutive s) ----
    mainloop_128x192<false>(srcp, ldso, &SMEM[0][0], &SMEM[1][0], l15, quad, wm, wn, acc);
    int sblk = (m0 & 4095) + wm + quad * 4;
#pragma unroll
    for (int j = 0; j < 6; ++j) {
      int n_j = n0 + wn + j * 16 + l15;
      float bv = bias[n_j];
      int h = (n_j >> 6) & 15, d = n_j & 63;
      int vbase = ((b * 16 + h) * 64 + d) * 4096;
#pragma unroll
      for (int i = 0; i < 4; ++i) {
        int s = sblk + i * 16;
        f32x4 a = acc[i * 6 + j];
        ushort4 pk;
        pk.x = f2bf(a[0] + bv);
        pk.y = f2bf(a[1] + bv);
        pk.z = f2bf(a[2] + bv);
        pk.w = f2bf(a[3] + bv);
        *(ushort4*)(Vtb + vbase + s) = pk;
      }
    }
  } else {
    // ---- mixed K/V block (n0=1920): V orientation; per-j select V-vec / K-scalar ----
    mainloop_128x192<false>(srcp, ldso, &SMEM[0][0], &SMEM[1][0], l15, quad, wm, wn, acc);
#pragma unroll
    for (int j = 0; j < 6; ++j) {
      int ng = n0 + wn + j * 16;                   // wave-uniform per j
      if (ng >= 2048) {
        int n_j = ng + l15;
        float bv = bias[n_j];
        int h = (n_j >> 6) & 15, d = n_j & 63;
        int vbase = ((b * 16 + h) * 64 + d) * 4096;
        int sblk = (m0 & 4095) + wm + quad * 4;
#pragma unroll
        for (int i = 0; i < 4; ++i) {
          int s = sblk + i * 16;
          f32x4 a = acc[i * 6 + j];
          ushort4 pk;
          pk.x = f2bf(a[0] + bv);
          pk.y = f2bf(a[1] + bv);
          pk.z = f2bf(a[2] + bv);
          pk.w = f2bf(a[3] + bv);
          *(ushort4*)(Vtb + vbase + s) = pk;
        }
      } else {
        // K part, V orientation: m on quad*4+r, n on l15 -> scalar stores (rare: 64 blocks)
        int n_j = ng + l15;
        float bv = bias[n_j];
        int h = (n_j >> 6) & 15, d = n_j & 63;
        int kbase = (b * 16 + h) * 4096 * 64 + d;
#pragma unroll
        for (int i = 0; i < 4; ++i) {
          f32x4 a = acc[i * 6 + j];
#pragma unroll
          for (int r = 0; r < 4; ++r) {
            int s = (m0 & 4095) + wm + i * 16 + quad * 4 + r;
            Kb[kbase + s * 64] = f2bf(a[r] + bv);
          }
        }
      }
    }
  }
}

// ---------------- fused block-diagonal attention (r3-verified, unchanged) ----------------
#define LDP 72

__global__ __launch_bounds__(256) void attn_k(
    const unsigned short* __restrict__ Qb,
    const unsigned short* __restrict__ Kb,
    const unsigned short* __restrict__ Vtb,
    unsigned short* __restrict__ Ab) {
  __shared__ unsigned short KV[2][2][4096];
  __shared__ unsigned short Ps[4][16 * LDP];

  int tid = threadIdx.x;
  int idx = blockIdx.x;
  // XCD-coherent decode: sharers of one K/V segment are idx, idx+8, idx+16,
  // idx+24 -> same XCD under round-robin dispatch (idx mod 8 fixed).
  int grp = ((idx >> 5) << 3) | (idx & 7);
  int qblk = (idx >> 3) & 3;
  int seg = grp & 3, h = (grp >> 2) & 15, b = grp >> 6;
  int w = tid >> 6, lane = tid & 63, l15 = lane & 15, quad = lane >> 4;
  int bh = b * 16 + h;
  int q0 = seg * 1024 + qblk * 256 + w * 64;

  const unsigned short* Kg = Kb + (bh * 4096 + seg * 1024) * 64;
  const unsigned short* Vg = Vtb + bh * 64 * 4096 + seg * 1024;

  int r0 = w * 16 + (lane >> 3);
  int cs = ((lane & 7) ^ (lane >> 3)) * 8;

  const unsigned short* Qg = Qb + (bh * 4096 + q0) * 64;
  bf16x8 qf[4][2];
#pragma unroll
  for (int qb = 0; qb < 4; ++qb)
#pragma unroll
    for (int kk = 0; kk < 2; ++kk)
      qf[qb][kk] = *(const bf16x8*)(Qg + (qb * 16 + l15) * 64 + kk * 32 + quad * 8);

  f32x4 o[4][4] = {};
  float lsum[4] = {0.f, 0.f, 0.f, 0.f};
  unsigned short* Pw = Ps[w];

  {
    unsigned short* dk = &KV[0][0][w * 1024];
    unsigned short* dv = &KV[0][1][w * 1024];
    gload16(Kg + r0 * 64 + cs, dk);
    gload16(Kg + (r0 + 8) * 64 + cs, dk + 512);
    gload16(Vg + r0 * 4096 + cs, dv);
    gload16(Vg + (r0 + 8) * 4096 + cs, dv + 512);
  }

#pragma unroll 2
  for (int kt = 0; kt < 16; ++kt) {
    int cur = kt & 1;
    __syncthreads();
    if (kt < 15) {
      unsigned short* dk = &KV[cur ^ 1][0][w * 1024];
      unsigned short* dv = &KV[cur ^ 1][1][w * 1024];
      const unsigned short* kN = Kg + (kt + 1) * 4096;
      const unsigned short* vN = Vg + (kt + 1) * 64;
      gload16(kN + r0 * 64 + cs, dk);
      gload16(kN + (r0 + 8) * 64 + cs, dk + 512);
      gload16(vN + r0 * 4096 + cs, dv);
      gload16(vN + (r0 + 8) * 4096 + cs, dv + 512);
    }
    const unsigned short* Kt = KV[cur][0];
    const unsigned short* Vt = KV[cur][1];

    uint2 pp[4][4];
#pragma unroll
    for (int half = 0; half < 2; ++half) {
      f32x4 st[2][4] = {};
#pragma unroll
      for (int kk = 0; kk < 2; ++kk) {
        int cg = kk * 4 + quad;
        bf16x8 kf0 = *(const bf16x8*)(Kt + SWZ(half * 32 + l15, cg));
        bf16x8 kf1 = *(const bf16x8*)(Kt + SWZ(half * 32 + 16 + l15, cg));
#pragma unroll
        for (int qb = 0; qb < 4; ++qb) {
          st[0][qb] = __builtin_amdgcn_mfma_f32_16x16x32_bf16(kf0, qf[qb][kk], st[0][qb], 0, 0, 0);
          st[1][qb] = __builtin_amdgcn_mfma_f32_16x16x32_bf16(kf1, qf[qb][kk], st[1][qb], 0, 0, 0);
        }
      }
#pragma unroll
      for (int kb = 0; kb < 2; ++kb)
#pragma unroll
        for (int qb = 0; qb < 4; ++qb) {
          f32x4 s = st[kb][qb];
          float p0 = fast_exp2(s[0]), p1 = fast_exp2(s[1]);
          float p2 = fast_exp2(s[2]), p3 = fast_exp2(s[3]);
          lsum[qb] += (p0 + p1) + (p2 + p3);
          uint2 d;
          d.x = pack_bf2(p0, p1);
          d.y = pack_bf2(p2, p3);
          pp[qb][half * 2 + kb] = d;
        }
    }

    bf16x8 vf[2][4];
#pragma unroll
    for (int kk = 0; kk < 2; ++kk)
#pragma unroll
      for (int db = 0; db < 4; ++db)
        vf[kk][db] = *(const bf16x8*)(Vt + SWZ(db * 16 + l15, kk * 4 + quad));
#pragma unroll
    for (int qb = 0; qb < 4; ++qb) {
#pragma unroll
      for (int g = 0; g < 4; ++g)
        *(uint2*)(Pw + l15 * LDP + g * 16 + quad * 4) = pp[qb][g];
#pragma unroll
      for (int kk = 0; kk < 2; ++kk) {
        bf16x8 pa = *(const bf16x8*)(Pw + l15 * LDP + kk * 32 + quad * 8);
#pragma unroll
        for (int db = 0; db < 4; ++db)
          o[qb][db] = __builtin_amdgcn_mfma_f32_16x16x32_bf16(pa, vf[kk][db], o[qb][db], 0, 0, 0);
      }
    }
  }

#pragma unroll
  for (int qb = 0; qb < 4; ++qb) {
    lsum[qb] += __shfl_xor(lsum[qb], 16);
    lsum[qb] += __shfl_xor(lsum[qb], 32);
  }

  float* Wf = (float*)(&KV[0][0][0]) + w * 1024;
#pragma unroll
  for (int qb = 0; qb < 4; ++qb) {
#pragma unroll
    for (int db = 0; db < 4; ++db)
#pragma unroll
      for (int r = 0; r < 4; ++r)
        Wf[(quad * 4 + r) * 64 + db * 16 + l15] = o[qb][db][r];
    float inv = 1.0f / lsum[qb];
    float4 x0 = *(float4*)(Wf + l15 * 64 + quad * 8);
    float4 x1 = *(float4*)(Wf + l15 * 64 + quad * 8 + 4);
    float4 x2 = *(float4*)(Wf + l15 * 64 + (quad + 4) * 8);
    float4 x3 = *(float4*)(Wf + l15 * 64 + (quad + 4) * 8 + 4);
    uint4 u0, u1;
    u0.x = pack_bf2(x0.x * inv, x0.y * inv);
    u0.y = pack_bf2(x0.z * inv, x0.w * inv);
    u0.z = pack_bf2(x1.x * inv, x1.y * inv);
    u0.w = pack_bf2(x1.z * inv, x1.w * inv);
    u1.x = pack_bf2(x2.x * inv, x2.y * inv);
    u1.y = pack_bf2(x2.z * inv, x2.w * inv);
    u1.z = pack_bf2(x3.x * inv, x3.y * inv);
    u1.w = pack_bf2(x3.z * inv, x3.w * inv);
    int sg = q0 + qb * 16 + l15;
    int base = (b * 4096 + sg) * 1024 + h * 64;
    *(uint4*)(Ab + base + quad * 8) = u0;
    *(uint4*)(Ab + base + (quad + 4) * 8) = u1;
  }
}

// ---------------- GEMM2: out = Ab @ w_out^T + b_out (fp32 out), BK=64 ----------------
// Swapped operands: lane owns (m=l15, 4 consecutive n) -> float4 stores along n.
__global__ __launch_bounds__(256) void gemm_out(
    const unsigned short* __restrict__ A,
    const unsigned short* __restrict__ Bt,
    const float* __restrict__ bias,
    float* __restrict__ C) {
  const int K = 1024;
  __shared__ unsigned short As2[2][8192];
  __shared__ unsigned short Bs2[2][8192];
  int tid = threadIdx.x;
  int m0 = blockIdx.x * 128, n0 = blockIdx.y * 128;
  int w = tid >> 6, lane = tid & 63, l15 = lane & 15, quad = lane >> 4;
  int wm = (w & 1) * 64, wn = (w >> 1) * 64;

  f32x4 acc[4][4] = {};

  int rs = w * 32 + (lane >> 3);
  int cs = ((lane & 7) ^ (lane >> 3)) * 8;
  const unsigned short* Ag = A + (m0 + rs) * K + cs;
  const unsigned short* Bg = Bt + (n0 + rs) * K + cs;

  // prologue: stage tile 0 -> buf0
#pragma unroll
  for (int i = 0; i < 4; ++i) {
    gload16(Ag + i * 8 * K, &As2[0][0] + w * 2048 + i * 512);
    gload16(Bg + i * 8 * K, &Bs2[0][0] + w * 2048 + i * 512);
  }
#pragma unroll 1
  for (int kt2 = 0; kt2 < 16; kt2 += 2) {
#pragma unroll
    for (int half = 0; half < 2; ++half) {
      int kt = kt2 + half;
      unsigned short* Awr = half ? &As2[0][0] : &As2[1][0];
      unsigned short* Bwr = half ? &Bs2[0][0] : &Bs2[1][0];
      const unsigned short* Ard = half ? &As2[1][0] : &As2[0][0];
      const unsigned short* Brd = half ? &Bs2[1][0] : &Bs2[0][0];
      if (kt < 15) {
#pragma unroll
        for (int i = 0; i < 4; ++i) {
          gload16(Ag + i * 8 * K + (kt + 1) * 64, Awr + w * 2048 + i * 512);
          gload16(Bg + i * 8 * K + (kt + 1) * 64, Bwr + w * 2048 + i * 512);
        }
        asm volatile("s_waitcnt vmcnt(8)" ::: "memory");
      } else {
        asm volatile("s_waitcnt vmcnt(0)" ::: "memory");
      }
      __builtin_amdgcn_s_barrier();
      __builtin_amdgcn_sched_barrier(0);
#pragma unroll
      for (int kk = 0; kk < 2; ++kk) {
        int swk = (((kk * 4 + quad) ^ (l15 & 7))) * 8;
        bf16x8 af[4], bfr[4];
#pragma unroll
        for (int i = 0; i < 4; ++i) af[i] = *(const bf16x8*)(Ard + (wm + i * 16 + l15) * 64 + swk);
#pragma unroll
        for (int j = 0; j < 4; ++j) bfr[j] = *(const bf16x8*)(Brd + (wn + j * 16 + l15) * 64 + swk);
#pragma unroll
        for (int j = 0; j < 4; ++j)
#pragma unroll
          for (int i = 0; i < 4; ++i)
            acc[j][i] = __builtin_amdgcn_mfma_f32_16x16x32_bf16(bfr[j], af[i], acc[j][i], 0, 0, 0);
      }
      __builtin_amdgcn_s_barrier();
    }
  }

#pragma unroll
  for (int j = 0; j < 4; ++j) {
    int nb = n0 + wn + j * 16 + quad * 4;        // 4 consecutive n in regs
    float4 bv = *(const float4*)(bias + nb);
#pragma unroll
    for (int i = 0; i < 4; ++i) {
      int m = m0 + wm + i * 16 + l15;
      float4 ov;
      ov.x = acc[j][i][0] + bv.x;
      ov.y = acc[j][i][1] + bv.y;
      ov.z = acc[j][i][2] + bv.z;
      ov.w = acc[j][i][3] + bv.w;
      *(float4*)(C + m * 1024 + nb) = ov;
    }
  }
}

// ---------------- launch ----------------
extern "C" void kernel_launch(void* const* d_in, const int* in_sizes, int n_in,
                              void* d_out, int out_size, void* d_ws, size_t ws_size,
                              hipStream_t stream) {
  const float* x     = (const float*)d_in[0];
  const float* w_qkv = (const float*)d_in[1];
  const float* b_qkv = (const float*)d_in[2];
  const float* w_out = (const float*)d_in[3];
  const float* b_out = (const float*)d_in[4];
  float* out = (float*)d_out;
  char* ws = (char*)d_ws;

  unsigned short* wqkvb = (unsigned short*)(ws);              //  6 MB [3072][1024]
  unsigned short* woutb = (unsigned short*)(ws + 6291456);    //  2 MB [1024][1024]
  unsigned short* Qb    = (unsigned short*)(ws + 8388608);    // 16 MB [b,h,s,d] (x SL2E)
  unsigned short* Kb    = (unsigned short*)(ws + 25165824);   // 16 MB [b,h,s,d]
  unsigned short* Vtb   = (unsigned short*)(ws + 41943040);   // 16 MB [b,h,d,s]
  unsigned short* xb    = (unsigned short*)(ws + 58720256);   // 16 MB (reused as Ab)
  unsigned short* Ab    = xb;

  f32_to_bf16_all<<<12288, 256, 0, stream>>>(x, w_qkv, w_out, xb, wqkvb, woutb);
  gemm_qkv<<<dim3(64, 16), 256, 0, stream>>>(xb, wqkvb, b_qkv, Qb, Kb, Vtb);
  attn_k<<<512, 256, 0, stream>>>(Qb, Kb, Vtb, Ab);
  gemm_out<<<dim3(64, 8), 256, 0, stream>>>(Ab, woutb, b_out, out);
}

// Round 12
// 241.622 us; speedup vs baseline: 1.0070x; 1.0070x over previous
//
#include <hip/hip_runtime.h>

typedef __bf16 bf16x8 __attribute__((ext_vector_type(8)));
typedef float f32x4 __attribute__((ext_vector_type(4)));

#define SL2E 0.18033688011112042f  // log2(e)/8, folded into Q at gemm_qkv epilogue

__device__ __forceinline__ unsigned short f2bf(float f) {
  union { float f; unsigned u; } v; v.f = f;
  unsigned r = v.u + 0x7fffu + ((v.u >> 16) & 1u);
  return (unsigned short)(r >> 16);
}

__device__ __forceinline__ float fast_exp2(float x) {
#if __has_builtin(__builtin_amdgcn_exp2f)
  return __builtin_amdgcn_exp2f(x);
#else
  return exp2f(x);
#endif
}

__device__ __forceinline__ unsigned pack_bf2(float lo, float hi) {
  union { float f; unsigned u; } a, b;
  a.f = lo; b.f = hi;
#if __has_builtin(__builtin_amdgcn_perm)
  return __builtin_amdgcn_perm(b.u + 0x7fffu, a.u + 0x7fffu, 0x07060302u);
#else
  return ((b.u + 0x7fffu) & 0xffff0000u) | ((a.u + 0x7fffu) >> 16);
#endif
}

// async global->LDS, 16B/lane; HW dest = readfirstlane(lds base) + lane*16
__device__ __forceinline__ void gload16(const unsigned short* g, unsigned short* l) {
  __builtin_amdgcn_global_load_lds(
      (const __attribute__((address_space(1))) unsigned int*)g,
      (__attribute__((address_space(3))) unsigned int*)l, 16, 0, 0);
}

// swizzled chunk address (shorts): row R (64-short rows), colgroup cg of 8 shorts
#define SWZ(r, cg) ((((r) * 8) + ((cg) ^ ((r) & 7))) * 8)

// ---------------- fused fp32 -> bf16 conversion (x, w_qkv, w_out) ----------------
__global__ __launch_bounds__(256) void f32_to_bf16_all(
    const float* __restrict__ x, const float* __restrict__ wq, const float* __restrict__ wo,
    unsigned short* __restrict__ xb, unsigned short* __restrict__ wqb, unsigned short* __restrict__ wob) {
  int i = blockIdx.x * 256 + threadIdx.x;  // quad index
  const float* src; unsigned short* dst; int off;
  if (i < 2097152) { src = x; dst = xb; off = i; }
  else if (i < 2883584) { src = wq; dst = wqb; off = i - 2097152; }
  else if (i < 3145728) { src = wo; dst = wob; off = i - 2883584; }
  else return;
  float4 v = ((const float4*)src)[off];
  ushort4 o;
  o.x = f2bf(v.x); o.y = f2bf(v.y); o.z = f2bf(v.z); o.w = f2bf(v.w);
  ((ushort4*)dst)[off] = o;
}

// ============ GEMM1: 256x192 block, BK=64, 8 waves of 64x96 (r8-measured: 62.0us) ============
// Best-measured gemm_qkv config (r8): LDS 112KB, 2-phase counted-vmcnt(7) dbuf.

template <bool SWAP>
__device__ __forceinline__ void tile_compute_6x4(
    const unsigned short* As_, const unsigned short* Bs_,
    int l15, int quad, int wm, int wn, f32x4* acc) {
#pragma unroll
  for (int kk = 0; kk < 2; ++kk) {
    int cg = kk * 4 + quad;
    bf16x8 af[4], bfr[6];
#pragma unroll
    for (int i = 0; i < 4; ++i) af[i] = *(const bf16x8*)(As_ + SWZ(wm + i * 16 + l15, cg));
#pragma unroll
    for (int j = 0; j < 6; ++j) bfr[j] = *(const bf16x8*)(Bs_ + SWZ(wn + j * 16 + l15, cg));
    if constexpr (SWAP) {
#pragma unroll
      for (int j = 0; j < 6; ++j)
#pragma unroll
        for (int i = 0; i < 4; ++i)
          acc[j * 4 + i] = __builtin_amdgcn_mfma_f32_16x16x32_bf16(bfr[j], af[i], acc[j * 4 + i], 0, 0, 0);
    } else {
#pragma unroll
      for (int i = 0; i < 4; ++i)
#pragma unroll
        for (int j = 0; j < 6; ++j)
          acc[i * 6 + j] = __builtin_amdgcn_mfma_f32_16x16x32_bf16(af[i], bfr[j], acc[i * 6 + j], 0, 0, 0);
    }
  }
}

template <bool SWAP>
__device__ __forceinline__ void mainloop_256x192(
    const unsigned short* const srcp[7], const int ldso[7],
    unsigned short* lds0, unsigned short* lds1,
    int l15, int quad, int wm, int wn, f32x4* acc) {
  // prologue: stage tile 0 -> buf0 (7 loads in flight per wave)
#pragma unroll
  for (int i = 0; i < 7; ++i) gload16(srcp[i], lds0 + ldso[i]);
#pragma unroll 1
  for (int t2 = 0; t2 < 16; t2 += 2) {
    // body A: stage t2+1 -> buf1; compute buf0
#pragma unroll
    for (int i = 0; i < 7; ++i) gload16(srcp[i] + (t2 + 1) * 64, lds1 + ldso[i]);
    asm volatile("s_waitcnt vmcnt(7)" ::: "memory");  // tile t2 landed; t2+1 in flight
    __builtin_amdgcn_s_barrier();
    __builtin_amdgcn_sched_barrier(0);
    tile_compute_6x4<SWAP>(lds0, lds0 + 16384, l15, quad, wm, wn, acc);
    __builtin_amdgcn_s_barrier();   // all waves done reading buf0 -> re-stageable
    // body B: stage t2+2 -> buf0; compute buf1
    if (t2 < 14) {
#pragma unroll
      for (int i = 0; i < 7; ++i) gload16(srcp[i] + (t2 + 2) * 64, lds0 + ldso[i]);
      asm volatile("s_waitcnt vmcnt(7)" ::: "memory");
    } else {
      asm volatile("s_waitcnt vmcnt(0)" ::: "memory");  // last tile: nothing younger
    }
    __builtin_amdgcn_s_barrier();
    __builtin_amdgcn_sched_barrier(0);
    tile_compute_6x4<SWAP>(lds1, lds1 + 16384, l15, quad, wm, wn, acc);
    __builtin_amdgcn_s_barrier();
  }
}

// ---------------- GEMM1: qkv = x @ w_qkv^T + b, scatter to Q/K/Vt ----------------
__global__ __launch_bounds__(512, 2) void gemm_qkv(
    const unsigned short* __restrict__ A,
    const unsigned short* __restrict__ Bt,
    const float* __restrict__ bias,
    unsigned short* __restrict__ Qb,
    unsigned short* __restrict__ Kb,
    unsigned short* __restrict__ Vtb) {
  const int K = 1024;
  // buf layout (shorts): [0,16384) = A tile 256x64; [16384, 28672) = B tile 192x64
  __shared__ unsigned short SMEM[2][28672];
  int tid = threadIdx.x;
  int w = tid >> 6, lane = tid & 63, l15 = lane & 15, quad = lane >> 4;
  int m0 = blockIdx.x * 256, n0 = blockIdx.y * 192;
  int wm = (w & 3) * 64, wn = (w >> 2) * 96;
  int b = m0 >> 12;

  // staging slots: 56 instrs (A rows q*8.., q<32; B rows (q-32)*8..), 7 per wave
  int rlane = lane >> 3;
  int cs = ((lane & 7) ^ rlane) * 8;  // inverse-swizzle source colgroup
  const unsigned short* srcp[7];
  int ldso[7];
#pragma unroll
  for (int i = 0; i < 7; ++i) {
    int q = w * 7 + i;
    if (q < 32) { srcp[i] = A + (m0 + q * 8 + rlane) * K + cs; ldso[i] = q * 512; }
    else { srcp[i] = Bt + (n0 + (q - 32) * 8 + rlane) * K + cs; ldso[i] = 16384 + (q - 32) * 512; }
  }

  f32x4 acc[24] = {};

  bool pureV = (n0 >= 2048);
  bool mixed = (n0 < 2048) && (n0 + 192 > 2048);   // n0 == 1920 only

  if (!pureV && !mixed) {
    // ---- Q/K blocks (incl. Q/K straddle at n0=960): swapped operands ----
    mainloop_256x192<true>(srcp, ldso, &SMEM[0][0], &SMEM[1][0], l15, quad, wm, wn, acc);
    int s_base = (m0 & 4095) + wm;
#pragma unroll
    for (int j = 0; j < 6; ++j) {
      int ng = n0 + wn + j * 16;                   // 16-aligned, never crosses 1024
      int t = ng >> 10;                            // 0=Q, 1=K (per-j)
      unsigned short* dst = t ? Kb : Qb;
      float sc = t ? 1.0f : SL2E;
      int h = (ng >> 6) & 15;
      int d0 = (ng & 63) + quad * 4;
      float4 bv = *(const float4*)(bias + ng + quad * 4);
      int head_base = (b * 16 + h) * 4096 * 64;
#pragma unroll
      for (int i = 0; i < 8; ++i) {
        int s = s_base + i * 16 + l15;
        f32x4 a = acc[j * 4 + (i & 3)];
        if ((i >> 2) == 0 && 0) {}
        // note: 8 i-steps cover wm..wm+127? r8 used 4 (wave-tile m=64). keep 4.
      }
#pragma unroll
      for (int i = 0; i < 4; ++i) {
        int s = s_base + i * 16 + l15;
        f32x4 a = acc[j * 4 + i];
        ushort4 pk;
        pk.x = f2bf((a[0] + bv.x) * sc);
        pk.y = f2bf((a[1] + bv.y) * sc);
        pk.z = f2bf((a[2] + bv.z) * sc);
        pk.w = f2bf((a[3] + bv.w) * sc);
        *(ushort4*)(dst + head_base + s * 64 + d0) = pk;
      }
    }
  } else if (pureV) {
    // ---- pure V blocks: original orientation ----
    mainloop_256x192<false>(srcp, ldso, &SMEM[0][0], &SMEM[1][0], l15, quad, wm, wn, acc);
    int sblk = (m0 & 4095) + wm + quad * 4;
#pragma unroll
    for (int j = 0; j < 6; ++j) {
      int n_j = n0 + wn + j * 16 + l15;
      float bv = bias[n_j];
      int h = (n_j >> 6) & 15, d = n_j & 63;
      int vbase = ((b * 16 + h) * 64 + d) * 4096;
#pragma unroll
      for (int i = 0; i < 4; ++i) {
        int s = sblk + i * 16;
        f32x4 a = acc[i * 6 + j];
        ushort4 pk;
        pk.x = f2bf(a[0] + bv);
        pk.y = f2bf(a[1] + bv);
        pk.z = f2bf(a[2] + bv);
        pk.w = f2bf(a[3] + bv);
        *(ushort4*)(Vtb + vbase + s) = pk;
      }
    }
  } else {
    // ---- mixed K/V block (n0=1920): V orientation; per-j select V-vec / K-scalar ----
    mainloop_256x192<false>(srcp, ldso, &SMEM[0][0], &SMEM[1][0], l15, quad, wm, wn, acc);
#pragma unroll
    for (int j = 0; j < 6; ++j) {
      int ng = n0 + wn + j * 16;                   // wave-uniform per j
      if (ng >= 2048) {
        int n_j = ng + l15;
        float bv = bias[n_j];
        int h = (n_j >> 6) & 15, d = n_j & 63;
        int vbase = ((b * 16 + h) * 64 + d) * 4096;
        int sblk = (m0 & 4095) + wm + quad * 4;
#pragma unroll
        for (int i = 0; i < 4; ++i) {
          int s = sblk + i * 16;
          f32x4 a = acc[i * 6 + j];
          ushort4 pk;
          pk.x = f2bf(a[0] + bv);
          pk.y = f2bf(a[1] + bv);
          pk.z = f2bf(a[2] + bv);
          pk.w = f2bf(a[3] + bv);
          *(ushort4*)(Vtb + vbase + s) = pk;
        }
      } else {
        int n_j = ng + l15;
        float bv = bias[n_j];
        int h = (n_j >> 6) & 15, d = n_j & 63;
        int kbase = (b * 16 + h) * 4096 * 64 + d;
#pragma unroll
        for (int i = 0; i < 4; ++i) {
          f32x4 a = acc[i * 6 + j];
#pragma unroll
          for (int r = 0; r < 4; ++r) {
            int s = (m0 & 4095) + wm + i * 16 + quad * 4 + r;
            Kb[kbase + s * 64] = f2bf(a[r] + bv);
          }
        }
      }
    }
  }
}

// ---------------- fused block-diagonal attention ----------------
// r3-verified structure + ONE change: Ps double-buffered by qb parity, P-writes
// software-pipelined ahead of their reads (removes the in-order DS pipe's
// W->R->W->R serialization through one region). No setprio (m190: negative on
// barrier-locked blocks), no kf-hoist.
#define LDP 72

__global__ __launch_bounds__(256) void attn_k(
    const unsigned short* __restrict__ Qb,
    const unsigned short* __restrict__ Kb,
    const unsigned short* __restrict__ Vtb,
    unsigned short* __restrict__ Ab) {
  __shared__ unsigned short KV[2][2][4096];
  __shared__ unsigned short Ps[2][4][16 * LDP];  // [qb&1][wave][...]

  int tid = threadIdx.x;
  int idx = blockIdx.x;
  // XCD-coherent decode: sharers of one K/V segment are idx, idx+8, idx+16,
  // idx+24 -> same XCD under round-robin dispatch (idx mod 8 fixed).
  int grp = ((idx >> 5) << 3) | (idx & 7);
  int qblk = (idx >> 3) & 3;
  int seg = grp & 3, h = (grp >> 2) & 15, b = grp >> 6;
  int w = tid >> 6, lane = tid & 63, l15 = lane & 15, quad = lane >> 4;
  int bh = b * 16 + h;
  int q0 = seg * 1024 + qblk * 256 + w * 64;

  const unsigned short* Kg = Kb + (bh * 4096 + seg * 1024) * 64;
  const unsigned short* Vg = Vtb + bh * 64 * 4096 + seg * 1024;

  int r0 = w * 16 + (lane >> 3);
  int cs = ((lane & 7) ^ (lane >> 3)) * 8;

  const unsigned short* Qg = Qb + (bh * 4096 + q0) * 64;
  bf16x8 qf[4][2];
#pragma unroll
  for (int qb = 0; qb < 4; ++qb)
#pragma unroll
    for (int kk = 0; kk < 2; ++kk)
      qf[qb][kk] = *(const bf16x8*)(Qg + (qb * 16 + l15) * 64 + kk * 32 + quad * 8);

  f32x4 o[4][4] = {};
  float lsum[4] = {0.f, 0.f, 0.f, 0.f};
  unsigned short* Pw0 = Ps[0][w];
  unsigned short* Pw1 = Ps[1][w];

  {
    unsigned short* dk = &KV[0][0][w * 1024];
    unsigned short* dv = &KV[0][1][w * 1024];
    gload16(Kg + r0 * 64 + cs, dk);
    gload16(Kg + (r0 + 8) * 64 + cs, dk + 512);
    gload16(Vg + r0 * 4096 + cs, dv);
    gload16(Vg + (r0 + 8) * 4096 + cs, dv + 512);
  }

#pragma unroll 2
  for (int kt = 0; kt < 16; ++kt) {
    int cur = kt & 1;
    __syncthreads();
    if (kt < 15) {
      unsigned short* dk = &KV[cur ^ 1][0][w * 1024];
      unsigned short* dv = &KV[cur ^ 1][1][w * 1024];
      const unsigned short* kN = Kg + (kt + 1) * 4096;
      const unsigned short* vN = Vg + (kt + 1) * 64;
      gload16(kN + r0 * 64 + cs, dk);
      gload16(kN + (r0 + 8) * 64 + cs, dk + 512);
      gload16(vN + r0 * 4096 + cs, dv);
      gload16(vN + (r0 + 8) * 4096 + cs, dv + 512);
    }
    const unsigned short* Kt = KV[cur][0];
    const unsigned short* Vt = KV[cur][1];

    uint2 pp[4][4];
#pragma unroll
    for (int half = 0; half < 2; ++half) {
      f32x4 st[2][4] = {};
#pragma unroll
      for (int kk = 0; kk < 2; ++kk) {
        int cg = kk * 4 + quad;
        bf16x8 kf0 = *(const bf16x8*)(Kt + SWZ(half * 32 + l15, cg));
        bf16x8 kf1 = *(const bf16x8*)(Kt + SWZ(half * 32 + 16 + l15, cg));
#pragma unroll
        for (int qb = 0; qb < 4; ++qb) {
          st[0][qb] = __builtin_amdgcn_mfma_f32_16x16x32_bf16(kf0, qf[qb][kk], st[0][qb], 0, 0, 0);
          st[1][qb] = __builtin_amdgcn_mfma_f32_16x16x32_bf16(kf1, qf[qb][kk], st[1][qb], 0, 0, 0);
        }
      }
#pragma unroll
      for (int kb = 0; kb < 2; ++kb)
#pragma unroll
        for (int qb = 0; qb < 4; ++qb) {
          f32x4 s = st[kb][qb];
          float p0 = fast_exp2(s[0]), p1 = fast_exp2(s[1]);
          float p2 = fast_exp2(s[2]), p3 = fast_exp2(s[3]);
          lsum[qb] += (p0 + p1) + (p2 + p3);
          uint2 d;
          d.x = pack_bf2(p0, p1);
          d.y = pack_bf2(p2, p3);
          pp[qb][half * 2 + kb] = d;
        }
    }

    // stage P for qb=0 and qb=1 (disjoint parity regions) BEFORE the vf loads,
    // so the pa reads wait on long-completed writes (DS pipe is in-order per wave).
#pragma unroll
    for (int g = 0; g < 4; ++g) {
      *(uint2*)(Pw0 + l15 * LDP + g * 16 + quad * 4) = pp[0][g];
      *(uint2*)(Pw1 + l15 * LDP + g * 16 + quad * 4) = pp[1][g];
    }

    bf16x8 vf[2][4];
#pragma unroll
    for (int kk = 0; kk < 2; ++kk)
#pragma unroll
      for (int db = 0; db < 4; ++db)
        vf[kk][db] = *(const bf16x8*)(Vt + SWZ(db * 16 + l15, kk * 4 + quad));

#pragma unroll
    for (int qb = 0; qb < 4; ++qb) {
      unsigned short* Pw = (qb & 1) ? Pw1 : Pw0;
      bf16x8 pa0 = *(const bf16x8*)(Pw + l15 * LDP + quad * 8);
      bf16x8 pa1 = *(const bf16x8*)(Pw + l15 * LDP + 32 + quad * 8);
      if (qb < 2) {
        // refill this parity region for qb+2; per-wave in-order DS pipe means
        // these writes land after the pa reads above have completed.
#pragma unroll
        for (int g = 0; g < 4; ++g)
          *(uint2*)(Pw + l15 * LDP + g * 16 + quad * 4) = pp[qb + 2][g];
      }
#pragma unroll
      for (int db = 0; db < 4; ++db)
        o[qb][db] = __builtin_amdgcn_mfma_f32_16x16x32_bf16(pa0, vf[0][db], o[qb][db], 0, 0, 0);
#pragma unroll
      for (int db = 0; db < 4; ++db)
        o[qb][db] = __builtin_amdgcn_mfma_f32_16x16x32_bf16(pa1, vf[1][db], o[qb][db], 0, 0, 0);
    }
  }

#pragma unroll
  for (int qb = 0; qb < 4; ++qb) {
    lsum[qb] += __shfl_xor(lsum[qb], 16);
    lsum[qb] += __shfl_xor(lsum[qb], 32);
  }

  float* Wf = (float*)(&KV[0][0][0]) + w * 1024;
#pragma unroll
  for (int qb = 0; qb < 4; ++qb) {
#pragma unroll
    for (int db = 0; db < 4; ++db)
#pragma unroll
      for (int r = 0; r < 4; ++r)
        Wf[(quad * 4 + r) * 64 + db * 16 + l15] = o[qb][db][r];
    float inv = 1.0f / lsum[qb];
    float4 x0 = *(float4*)(Wf + l15 * 64 + quad * 8);
    float4 x1 = *(float4*)(Wf + l15 * 64 + quad * 8 + 4);
    float4 x2 = *(float4*)(Wf + l15 * 64 + (quad + 4) * 8);
    float4 x3 = *(float4*)(Wf + l15 * 64 + (quad + 4) * 8 + 4);
    uint4 u0, u1;
    u0.x = pack_bf2(x0.x * inv, x0.y * inv);
    u0.y = pack_bf2(x0.z * inv, x0.w * inv);
    u0.z = pack_bf2(x1.x * inv, x1.y * inv);
    u0.w = pack_bf2(x1.z * inv, x1.w * inv);
    u1.x = pack_bf2(x2.x * inv, x2.y * inv);
    u1.y = pack_bf2(x2.z * inv, x2.w * inv);
    u1.z = pack_bf2(x3.x * inv, x3.y * inv);
    u1.w = pack_bf2(x3.z * inv, x3.w * inv);
    int sg = q0 + qb * 16 + l15;
    int base = (b * 4096 + sg) * 1024 + h * 64;
    *(uint4*)(Ab + base + quad * 8) = u0;
    *(uint4*)(Ab + base + (quad + 4) * 8) = u1;
  }
}

// ---------------- GEMM2: out = Ab @ w_out^T + b_out (fp32 out), BK=64 ----------------
// Swapped operands: lane owns (m=l15, 4 consecutive n) -> float4 stores along n.
__global__ __launch_bounds__(256) void gemm_out(
    const unsigned short* __restrict__ A,
    const unsigned short* __restrict__ Bt,
    const float* __restrict__ bias,
    float* __restrict__ C) {
  const int K = 1024;
  __shared__ unsigned short As2[2][8192];
  __shared__ unsigned short Bs2[2][8192];
  int tid = threadIdx.x;
  int m0 = blockIdx.x * 128, n0 = blockIdx.y * 128;
  int w = tid >> 6, lane = tid & 63, l15 = lane & 15, quad = lane >> 4;
  int wm = (w & 1) * 64, wn = (w >> 1) * 64;

  f32x4 acc[4][4] = {};

  int rs = w * 32 + (lane >> 3);
  int cs = ((lane & 7) ^ (lane >> 3)) * 8;
  const unsigned short* Ag = A + (m0 + rs) * K + cs;
  const unsigned short* Bg = Bt + (n0 + rs) * K + cs;

  // prologue: stage tile 0 -> buf0
#pragma unroll
  for (int i = 0; i < 4; ++i) {
    gload16(Ag + i * 8 * K, &As2[0][0] + w * 2048 + i * 512);
    gload16(Bg + i * 8 * K, &Bs2[0][0] + w * 2048 + i * 512);
  }
#pragma unroll 1
  for (int kt2 = 0; kt2 < 16; kt2 += 2) {
#pragma unroll
    for (int half = 0; half < 2; ++half) {
      int kt = kt2 + half;
      unsigned short* Awr = half ? &As2[0][0] : &As2[1][0];
      unsigned short* Bwr = half ? &Bs2[0][0] : &Bs2[1][0];
      const unsigned short* Ard = half ? &As2[1][0] : &As2[0][0];
      const unsigned short* Brd = half ? &Bs2[1][0] : &Bs2[0][0];
      if (kt < 15) {
#pragma unroll
        for (int i = 0; i < 4; ++i) {
          gload16(Ag + i * 8 * K + (kt + 1) * 64, Awr + w * 2048 + i * 512);
          gload16(Bg + i * 8 * K + (kt + 1) * 64, Bwr + w * 2048 + i * 512);
        }
        asm volatile("s_waitcnt vmcnt(8)" ::: "memory");
      } else {
        asm volatile("s_waitcnt vmcnt(0)" ::: "memory");
      }
      __builtin_amdgcn_s_barrier();
      __builtin_amdgcn_sched_barrier(0);
#pragma unroll
      for (int kk = 0; kk < 2; ++kk) {
        int swk = (((kk * 4 + quad) ^ (l15 & 7))) * 8;
        bf16x8 af[4], bfr[4];
#pragma unroll
        for (int i = 0; i < 4; ++i) af[i] = *(const bf16x8*)(Ard + (wm + i * 16 + l15) * 64 + swk);
#pragma unroll
        for (int j = 0; j < 4; ++j) bfr[j] = *(const bf16x8*)(Brd + (wn + j * 16 + l15) * 64 + swk);
#pragma unroll
        for (int j = 0; j < 4; ++j)
#pragma unroll
          for (int i = 0; i < 4; ++i)
            acc[j][i] = __builtin_amdgcn_mfma_f32_16x16x32_bf16(bfr[j], af[i], acc[j][i], 0, 0, 0);
      }
      __builtin_amdgcn_s_barrier();
    }
  }

#pragma unroll
  for (int j = 0; j < 4; ++j) {
    int nb = n0 + wn + j * 16 + quad * 4;        // 4 consecutive n in regs
    float4 bv = *(const float4*)(bias + nb);
#pragma unroll
    for (int i = 0; i < 4; ++i) {
      int m = m0 + wm + i * 16 + l15;
      float4 ov;
      ov.x = acc[j][i][0] + bv.x;
      ov.y = acc[j][i][1] + bv.y;
      ov.z = acc[j][i][2] + bv.z;
      ov.w = acc[j][i][3] + bv.w;
      *(float4*)(C + m * 1024 + nb) = ov;
    }
  }
}

// ---------------- launch ----------------
extern "C" void kernel_launch(void* const* d_in, const int* in_sizes, int n_in,
                              void* d_out, int out_size, void* d_ws, size_t ws_size,
                              hipStream_t stream) {
  const float* x     = (const float*)d_in[0];
  const float* w_qkv = (const float*)d_in[1];
  const float* b_qkv = (const float*)d_in[2];
  const float* w_out = (const float*)d_in[3];
  const float* b_out = (const float*)d_in[4];
  float* out = (float*)d_out;
  char* ws = (char*)d_ws;

  unsigned short* wqkvb = (unsigned short*)(ws);              //  6 MB [3072][1024]
  unsigned short* woutb = (unsigned short*)(ws + 6291456);    //  2 MB [1024][1024]
  unsigned short* Qb    = (unsigned short*)(ws + 8388608);    // 16 MB [b,h,s,d] (x SL2E)
  unsigned short* Kb    = (unsigned short*)(ws + 25165824);   // 16 MB [b,h,s,d]
  unsigned short* Vtb   = (unsigned short*)(ws + 41943040);   // 16 MB [b,h,d,s]
  unsigned short* xb    = (unsigned short*)(ws + 58720256);   // 16 MB (reused as Ab)
  unsigned short* Ab    = xb;

  f32_to_bf16_all<<<12288, 256, 0, stream>>>(x, w_qkv, w_out, xb, wqkvb, woutb);
  gemm_qkv<<<dim3(32, 16), 512, 0, stream>>>(xb, wqkvb, b_qkv, Qb, Kb, Vtb);
  attn_k<<<512, 256, 0, stream>>>(Qb, Kb, Vtb, Ab);
  gemm_out<<<dim3(64, 8), 256, 0, stream>>>(Ab, woutb, b_out, out);
}

// Round 13
// 227.245 us; speedup vs baseline: 1.0707x; 1.0633x over previous
//
#include <hip/hip_runtime.h>

typedef __bf16 bf16x8 __attribute__((ext_vector_type(8)));
typedef float f32x4 __attribute__((ext_vector_type(4)));

#define SL2E 0.18033688011112042f  // log2(e)/8, folded into Q at gemm_qkv epilogue

__device__ __forceinline__ unsigned short f2bf(float f) {
  union { float f; unsigned u; } v; v.f = f;
  unsigned r = v.u + 0x7fffu + ((v.u >> 16) & 1u);
  return (unsigned short)(r >> 16);
}

__device__ __forceinline__ float fast_exp2(float x) {
#if __has_builtin(__builtin_amdgcn_exp2f)
  return __builtin_amdgcn_exp2f(x);
#else
  return exp2f(x);
#endif
}

__device__ __forceinline__ unsigned pack_bf2(float lo, float hi) {
  union { float f; unsigned u; } a, b;
  a.f = lo; b.f = hi;
#if __has_builtin(__builtin_amdgcn_perm)
  return __builtin_amdgcn_perm(b.u + 0x7fffu, a.u + 0x7fffu, 0x07060302u);
#else
  return ((b.u + 0x7fffu) & 0xffff0000u) | ((a.u + 0x7fffu) >> 16);
#endif
}

// async global->LDS, 16B/lane; HW dest = readfirstlane(lds base) + lane*16
__device__ __forceinline__ void gload16(const unsigned short* g, unsigned short* l) {
  __builtin_amdgcn_global_load_lds(
      (const __attribute__((address_space(1))) unsigned int*)g,
      (__attribute__((address_space(3))) unsigned int*)l, 16, 0, 0);
}

// swizzled chunk address (shorts): row R (64-short rows), colgroup cg of 8 shorts
#define SWZ(r, cg) ((((r) * 8) + ((cg) ^ ((r) & 7))) * 8)

// ---------------- fused fp32 -> bf16 conversion (x, w_qkv, w_out) ----------------
__global__ __launch_bounds__(256) void f32_to_bf16_all(
    const float* __restrict__ x, const float* __restrict__ wq, const float* __restrict__ wo,
    unsigned short* __restrict__ xb, unsigned short* __restrict__ wqb, unsigned short* __restrict__ wob) {
  int i = blockIdx.x * 256 + threadIdx.x;  // quad index
  const float* src; unsigned short* dst; int off;
  if (i < 2097152) { src = x; dst = xb; off = i; }
  else if (i < 2883584) { src = wq; dst = wqb; off = i - 2097152; }
  else if (i < 3145728) { src = wo; dst = wob; off = i - 2883584; }
  else return;
  float4 v = ((const float4*)src)[off];
  ushort4 o;
  o.x = f2bf(v.x); o.y = f2bf(v.y); o.z = f2bf(v.z); o.w = f2bf(v.w);
  ((ushort4*)dst)[off] = o;
}

// ============ GEMM1: 256x192 block, BK=64, 8 waves of 64x96 (r8-measured: 62.0us) ============
// Best-measured gemm_qkv config (r8): LDS 112KB, 2-phase counted-vmcnt(7) dbuf.

template <bool SWAP>
__device__ __forceinline__ void tile_compute_6x4(
    const unsigned short* As_, const unsigned short* Bs_,
    int l15, int quad, int wm, int wn, f32x4* acc) {
#pragma unroll
  for (int kk = 0; kk < 2; ++kk) {
    int cg = kk * 4 + quad;
    bf16x8 af[4], bfr[6];
#pragma unroll
    for (int i = 0; i < 4; ++i) af[i] = *(const bf16x8*)(As_ + SWZ(wm + i * 16 + l15, cg));
#pragma unroll
    for (int j = 0; j < 6; ++j) bfr[j] = *(const bf16x8*)(Bs_ + SWZ(wn + j * 16 + l15, cg));
    if constexpr (SWAP) {
#pragma unroll
      for (int j = 0; j < 6; ++j)
#pragma unroll
        for (int i = 0; i < 4; ++i)
          acc[j * 4 + i] = __builtin_amdgcn_mfma_f32_16x16x32_bf16(bfr[j], af[i], acc[j * 4 + i], 0, 0, 0);
    } else {
#pragma unroll
      for (int i = 0; i < 4; ++i)
#pragma unroll
        for (int j = 0; j < 6; ++j)
          acc[i * 6 + j] = __builtin_amdgcn_mfma_f32_16x16x32_bf16(af[i], bfr[j], acc[i * 6 + j], 0, 0, 0);
    }
  }
}

template <bool SWAP>
__device__ __forceinline__ void mainloop_256x192(
    const unsigned short* const srcp[7], const int ldso[7],
    unsigned short* lds0, unsigned short* lds1,
    int l15, int quad, int wm, int wn, f32x4* acc) {
  // prologue: stage tile 0 -> buf0 (7 loads in flight per wave)
#pragma unroll
  for (int i = 0; i < 7; ++i) gload16(srcp[i], lds0 + ldso[i]);
#pragma unroll 1
  for (int t2 = 0; t2 < 16; t2 += 2) {
    // body A: stage t2+1 -> buf1; compute buf0
#pragma unroll
    for (int i = 0; i < 7; ++i) gload16(srcp[i] + (t2 + 1) * 64, lds1 + ldso[i]);
    asm volatile("s_waitcnt vmcnt(7)" ::: "memory");  // tile t2 landed; t2+1 in flight
    __builtin_amdgcn_s_barrier();
    __builtin_amdgcn_sched_barrier(0);
    tile_compute_6x4<SWAP>(lds0, lds0 + 16384, l15, quad, wm, wn, acc);
    __builtin_amdgcn_s_barrier();   // all waves done reading buf0 -> re-stageable
    // body B: stage t2+2 -> buf0; compute buf1
    if (t2 < 14) {
#pragma unroll
      for (int i = 0; i < 7; ++i) gload16(srcp[i] + (t2 + 2) * 64, lds0 + ldso[i]);
      asm volatile("s_waitcnt vmcnt(7)" ::: "memory");
    } else {
      asm volatile("s_waitcnt vmcnt(0)" ::: "memory");  // last tile: nothing younger
    }
    __builtin_amdgcn_s_barrier();
    __builtin_amdgcn_sched_barrier(0);
    tile_compute_6x4<SWAP>(lds1, lds1 + 16384, l15, quad, wm, wn, acc);
    __builtin_amdgcn_s_barrier();
  }
}

// ---------------- GEMM1: qkv = x @ w_qkv^T + b, scatter to Q/K/Vt ----------------
__global__ __launch_bounds__(512, 2) void gemm_qkv(
    const unsigned short* __restrict__ A,
    const unsigned short* __restrict__ Bt,
    const float* __restrict__ bias,
    unsigned short* __restrict__ Qb,
    unsigned short* __restrict__ Kb,
    unsigned short* __restrict__ Vtb) {
  const int K = 1024;
  // buf layout (shorts): [0,16384) = A tile 256x64; [16384, 28672) = B tile 192x64
  __shared__ unsigned short SMEM[2][28672];
  int tid = threadIdx.x;
  int w = tid >> 6, lane = tid & 63, l15 = lane & 15, quad = lane >> 4;
  int m0 = blockIdx.x * 256, n0 = blockIdx.y * 192;
  int wm = (w & 3) * 64, wn = (w >> 2) * 96;
  int b = m0 >> 12;

  // staging slots: 56 instrs (A rows q*8.., q<32; B rows (q-32)*8..), 7 per wave
  int rlane = lane >> 3;
  int cs = ((lane & 7) ^ rlane) * 8;  // inverse-swizzle source colgroup
  const unsigned short* srcp[7];
  int ldso[7];
#pragma unroll
  for (int i = 0; i < 7; ++i) {
    int q = w * 7 + i;
    if (q < 32) { srcp[i] = A + (m0 + q * 8 + rlane) * K + cs; ldso[i] = q * 512; }
    else { srcp[i] = Bt + (n0 + (q - 32) * 8 + rlane) * K + cs; ldso[i] = 16384 + (q - 32) * 512; }
  }

  f32x4 acc[24] = {};

  bool pureV = (n0 >= 2048);
  bool mixed = (n0 < 2048) && (n0 + 192 > 2048);   // n0 == 1920 only

  if (!pureV && !mixed) {
    // ---- Q/K blocks (incl. Q/K straddle at n0=960): swapped operands ----
    mainloop_256x192<true>(srcp, ldso, &SMEM[0][0], &SMEM[1][0], l15, quad, wm, wn, acc);
    int s_base = (m0 & 4095) + wm;
#pragma unroll
    for (int j = 0; j < 6; ++j) {
      int ng = n0 + wn + j * 16;                   // 16-aligned, never crosses 1024
      int t = ng >> 10;                            // 0=Q, 1=K (per-j)
      unsigned short* dst = t ? Kb : Qb;
      float sc = t ? 1.0f : SL2E;
      int h = (ng >> 6) & 15;
      int d0 = (ng & 63) + quad * 4;
      float4 bv = *(const float4*)(bias + ng + quad * 4);
      int head_base = (b * 16 + h) * 4096 * 64;
#pragma unroll
      for (int i = 0; i < 4; ++i) {
        int s = s_base + i * 16 + l15;
        f32x4 a = acc[j * 4 + i];
        ushort4 pk;
        pk.x = f2bf((a[0] + bv.x) * sc);
        pk.y = f2bf((a[1] + bv.y) * sc);
        pk.z = f2bf((a[2] + bv.z) * sc);
        pk.w = f2bf((a[3] + bv.w) * sc);
        *(ushort4*)(dst + head_base + s * 64 + d0) = pk;
      }
    }
  } else if (pureV) {
    // ---- pure V blocks: original orientation ----
    mainloop_256x192<false>(srcp, ldso, &SMEM[0][0], &SMEM[1][0], l15, quad, wm, wn, acc);
    int sblk = (m0 & 4095) + wm + quad * 4;
#pragma unroll
    for (int j = 0; j < 6; ++j) {
      int n_j = n0 + wn + j * 16 + l15;
      float bv = bias[n_j];
      int h = (n_j >> 6) & 15, d = n_j & 63;
      int vbase = ((b * 16 + h) * 64 + d) * 4096;
#pragma unroll
      for (int i = 0; i < 4; ++i) {
        int s = sblk + i * 16;
        f32x4 a = acc[i * 6 + j];
        ushort4 pk;
        pk.x = f2bf(a[0] + bv);
        pk.y = f2bf(a[1] + bv);
        pk.z = f2bf(a[2] + bv);
        pk.w = f2bf(a[3] + bv);
        *(ushort4*)(Vtb + vbase + s) = pk;
      }
    }
  } else {
    // ---- mixed K/V block (n0=1920): V orientation; per-j select V-vec / K-scalar ----
    mainloop_256x192<false>(srcp, ldso, &SMEM[0][0], &SMEM[1][0], l15, quad, wm, wn, acc);
#pragma unroll
    for (int j = 0; j < 6; ++j) {
      int ng = n0 + wn + j * 16;                   // wave-uniform per j
      if (ng >= 2048) {
        int n_j = ng + l15;
        float bv = bias[n_j];
        int h = (n_j >> 6) & 15, d = n_j & 63;
        int vbase = ((b * 16 + h) * 64 + d) * 4096;
        int sblk = (m0 & 4095) + wm + quad * 4;
#pragma unroll
        for (int i = 0; i < 4; ++i) {
          int s = sblk + i * 16;
          f32x4 a = acc[i * 6 + j];
          ushort4 pk;
          pk.x = f2bf(a[0] + bv);
          pk.y = f2bf(a[1] + bv);
          pk.z = f2bf(a[2] + bv);
          pk.w = f2bf(a[3] + bv);
          *(ushort4*)(Vtb + vbase + s) = pk;
        }
      } else {
        int n_j = ng + l15;
        float bv = bias[n_j];
        int h = (n_j >> 6) & 15, d = n_j & 63;
        int kbase = (b * 16 + h) * 4096 * 64 + d;
#pragma unroll
        for (int i = 0; i < 4; ++i) {
          f32x4 a = acc[i * 6 + j];
#pragma unroll
          for (int r = 0; r < 4; ++r) {
            int s = (m0 & 4095) + wm + i * 16 + quad * 4 + r;
            Kb[kbase + s * 64] = f2bf(a[r] + bv);
          }
        }
      }
    }
  }
}

// ---------------- fused block-diagonal attention ----------------
// r12 counters: VGPR=156 (3 waves/SIMD cap), Occupancy 10.8% -> latency-bound.
// Restructure: 8 waves x 32 q-rows per 256-row block (512 threads). Per-wave
// state halves -> fits __launch_bounds__(512,4) 128-VGPR cap -> 4 waves/SIMD;
// 2 blocks/CU by LDS (KV 32KB + Ps 36KB) -> 16 waves/CU (2x r12).
// P staging: sequential r3 scheme, per-qb disjoint regions, all writes issued
// before vf loads (in-order DS pipe gives free write->read spacing).
#define LDP 72

__global__ __launch_bounds__(512, 4) void attn_k(
    const unsigned short* __restrict__ Qb,
    const unsigned short* __restrict__ Kb,
    const unsigned short* __restrict__ Vtb,
    unsigned short* __restrict__ Ab) {
  __shared__ unsigned short KV[2][2][4096];
  __shared__ unsigned short Ps[8][32 * LDP];   // per wave: 2 qb regions of 16*LDP

  int tid = threadIdx.x;
  int idx = blockIdx.x;
  // XCD-coherent decode: sharers of one K/V segment are idx, idx+8, idx+16,
  // idx+24 -> same XCD under round-robin dispatch (idx mod 8 fixed).
  int grp = ((idx >> 5) << 3) | (idx & 7);
  int qblk = (idx >> 3) & 3;
  int seg = grp & 3, h = (grp >> 2) & 15, b = grp >> 6;
  int w = tid >> 6, lane = tid & 63, l15 = lane & 15, quad = lane >> 4;
  int bh = b * 16 + h;
  int q0 = seg * 1024 + qblk * 256 + w * 32;

  const unsigned short* Kg = Kb + (bh * 4096 + seg * 1024) * 64;
  const unsigned short* Vg = Vtb + bh * 64 * 4096 + seg * 1024;

  int rlane = lane >> 3;
  int cs = ((lane & 7) ^ rlane) * 8;
  int srow = w * 8 + rlane;                     // this wave's staged chunk row

  const unsigned short* Qg = Qb + (bh * 4096 + q0) * 64;
  bf16x8 qf[2][2];
#pragma unroll
  for (int qb = 0; qb < 2; ++qb)
#pragma unroll
    for (int kk = 0; kk < 2; ++kk)
      qf[qb][kk] = *(const bf16x8*)(Qg + (qb * 16 + l15) * 64 + kk * 32 + quad * 8);

  f32x4 o[2][4] = {};
  float lsum[2] = {0.f, 0.f};
  unsigned short* Pw = Ps[w];

  // prologue: stage tile 0 (each wave: 1 K chunk + 1 V chunk)
  gload16(Kg + srow * 64 + cs, &KV[0][0][w * 512]);
  gload16(Vg + srow * 4096 + cs, &KV[0][1][w * 512]);

#pragma unroll 2
  for (int kt = 0; kt < 16; ++kt) {
    int cur = kt & 1;
    __syncthreads();
    if (kt < 15) {
      gload16(Kg + (kt + 1) * 4096 + srow * 64 + cs, &KV[cur ^ 1][0][w * 512]);
      gload16(Vg + (kt + 1) * 64 + srow * 4096 + cs, &KV[cur ^ 1][1][w * 512]);
    }
    const unsigned short* Kt = KV[cur][0];
    const unsigned short* Vt = KV[cur][1];

    uint2 pp[2][4];
#pragma unroll
    for (int half = 0; half < 2; ++half) {
      f32x4 st[2][2] = {};
#pragma unroll
      for (int kk = 0; kk < 2; ++kk) {
        int cg = kk * 4 + quad;
        bf16x8 kf0 = *(const bf16x8*)(Kt + SWZ(half * 32 + l15, cg));
        bf16x8 kf1 = *(const bf16x8*)(Kt + SWZ(half * 32 + 16 + l15, cg));
#pragma unroll
        for (int qb = 0; qb < 2; ++qb) {
          st[0][qb] = __builtin_amdgcn_mfma_f32_16x16x32_bf16(kf0, qf[qb][kk], st[0][qb], 0, 0, 0);
          st[1][qb] = __builtin_amdgcn_mfma_f32_16x16x32_bf16(kf1, qf[qb][kk], st[1][qb], 0, 0, 0);
        }
      }
#pragma unroll
      for (int kb = 0; kb < 2; ++kb)
#pragma unroll
        for (int qb = 0; qb < 2; ++qb) {
          f32x4 s = st[kb][qb];
          float p0 = fast_exp2(s[0]), p1 = fast_exp2(s[1]);
          float p2 = fast_exp2(s[2]), p3 = fast_exp2(s[3]);
          lsum[qb] += (p0 + p1) + (p2 + p3);
          uint2 d;
          d.x = pack_bf2(p0, p1);
          d.y = pack_bf2(p2, p3);
          pp[qb][half * 2 + kb] = d;
        }
    }

    // write P for both qb (disjoint regions) before any consumer ds_read
#pragma unroll
    for (int qb = 0; qb < 2; ++qb)
#pragma unroll
      for (int g = 0; g < 4; ++g)
        *(uint2*)(Pw + qb * 16 * LDP + l15 * LDP + g * 16 + quad * 4) = pp[qb][g];

#pragma unroll
    for (int kk = 0; kk < 2; ++kk) {
      bf16x8 vfk[4];
#pragma unroll
      for (int db = 0; db < 4; ++db)
        vfk[db] = *(const bf16x8*)(Vt + SWZ(db * 16 + l15, kk * 4 + quad));
#pragma unroll
      for (int qb = 0; qb < 2; ++qb) {
        bf16x8 pa = *(const bf16x8*)(Pw + qb * 16 * LDP + l15 * LDP + kk * 32 + quad * 8);
#pragma unroll
        for (int db = 0; db < 4; ++db)
          o[qb][db] = __builtin_amdgcn_mfma_f32_16x16x32_bf16(pa, vfk[db], o[qb][db], 0, 0, 0);
      }
    }
  }

#pragma unroll
  for (int qb = 0; qb < 2; ++qb) {
    lsum[qb] += __shfl_xor(lsum[qb], 16);
    lsum[qb] += __shfl_xor(lsum[qb], 32);
  }

  // all waves must be done reading KV before reusing the full 32KB as scratch
  __syncthreads();
  float* Wf = (float*)(&KV[0][0][0]) + w * 1024;
#pragma unroll
  for (int qb = 0; qb < 2; ++qb) {
#pragma unroll
    for (int db = 0; db < 4; ++db)
#pragma unroll
      for (int r = 0; r < 4; ++r)
        Wf[(quad * 4 + r) * 64 + db * 16 + l15] = o[qb][db][r];
    float inv = 1.0f / lsum[qb];
    float4 x0 = *(float4*)(Wf + l15 * 64 + quad * 8);
    float4 x1 = *(float4*)(Wf + l15 * 64 + quad * 8 + 4);
    float4 x2 = *(float4*)(Wf + l15 * 64 + (quad + 4) * 8);
    float4 x3 = *(float4*)(Wf + l15 * 64 + (quad + 4) * 8 + 4);
    uint4 u0, u1;
    u0.x = pack_bf2(x0.x * inv, x0.y * inv);
    u0.y = pack_bf2(x0.z * inv, x0.w * inv);
    u0.z = pack_bf2(x1.x * inv, x1.y * inv);
    u0.w = pack_bf2(x1.z * inv, x1.w * inv);
    u1.x = pack_bf2(x2.x * inv, x2.y * inv);
    u1.y = pack_bf2(x2.z * inv, x2.w * inv);
    u1.z = pack_bf2(x3.x * inv, x3.y * inv);
    u1.w = pack_bf2(x3.z * inv, x3.w * inv);
    int sg = q0 + qb * 16 + l15;
    int base = (b * 4096 + sg) * 1024 + h * 64;
    *(uint4*)(Ab + base + quad * 8) = u0;
    *(uint4*)(Ab + base + (quad + 4) * 8) = u1;
  }
}

// ---------------- GEMM2: out = Ab @ w_out^T + b_out (fp32 out), BK=64 ----------------
// Swapped operands: lane owns (m=l15, 4 consecutive n) -> float4 stores along n.
__global__ __launch_bounds__(256) void gemm_out(
    const unsigned short* __restrict__ A,
    const unsigned short* __restrict__ Bt,
    const float* __restrict__ bias,
    float* __restrict__ C) {
  const int K = 1024;
  __shared__ unsigned short As2[2][8192];
  __shared__ unsigned short Bs2[2][8192];
  int tid = threadIdx.x;
  int m0 = blockIdx.x * 128, n0 = blockIdx.y * 128;
  int w = tid >> 6, lane = tid & 63, l15 = lane & 15, quad = lane >> 4;
  int wm = (w & 1) * 64, wn = (w >> 1) * 64;

  f32x4 acc[4][4] = {};

  int rs = w * 32 + (lane >> 3);
  int cs = ((lane & 7) ^ (lane >> 3)) * 8;
  const unsigned short* Ag = A + (m0 + rs) * K + cs;
  const unsigned short* Bg = Bt + (n0 + rs) * K + cs;

  // prologue: stage tile 0 -> buf0
#pragma unroll
  for (int i = 0; i < 4; ++i) {
    gload16(Ag + i * 8 * K, &As2[0][0] + w * 2048 + i * 512);
    gload16(Bg + i * 8 * K, &Bs2[0][0] + w * 2048 + i * 512);
  }
#pragma unroll 1
  for (int kt2 = 0; kt2 < 16; kt2 += 2) {
#pragma unroll
    for (int half = 0; half < 2; ++half) {
      int kt = kt2 + half;
      unsigned short* Awr = half ? &As2[0][0] : &As2[1][0];
      unsigned short* Bwr = half ? &Bs2[0][0] : &Bs2[1][0];
      const unsigned short* Ard = half ? &As2[1][0] : &As2[0][0];
      const unsigned short* Brd = half ? &Bs2[1][0] : &Bs2[0][0];
      if (kt < 15) {
#pragma unroll
        for (int i = 0; i < 4; ++i) {
          gload16(Ag + i * 8 * K + (kt + 1) * 64, Awr + w * 2048 + i * 512);
          gload16(Bg + i * 8 * K + (kt + 1) * 64, Bwr + w * 2048 + i * 512);
        }
        asm volatile("s_waitcnt vmcnt(8)" ::: "memory");
      } else {
        asm volatile("s_waitcnt vmcnt(0)" ::: "memory");
      }
      __builtin_amdgcn_s_barrier();
      __builtin_amdgcn_sched_barrier(0);
#pragma unroll
      for (int kk = 0; kk < 2; ++kk) {
        int swk = (((kk * 4 + quad) ^ (l15 & 7))) * 8;
        bf16x8 af[4], bfr[4];
#pragma unroll
        for (int i = 0; i < 4; ++i) af[i] = *(const bf16x8*)(Ard + (wm + i * 16 + l15) * 64 + swk);
#pragma unroll
        for (int j = 0; j < 4; ++j) bfr[j] = *(const bf16x8*)(Brd + (wn + j * 16 + l15) * 64 + swk);
#pragma unroll
        for (int j = 0; j < 4; ++j)
#pragma unroll
          for (int i = 0; i < 4; ++i)
            acc[j][i] = __builtin_amdgcn_mfma_f32_16x16x32_bf16(bfr[j], af[i], acc[j][i], 0, 0, 0);
      }
      __builtin_amdgcn_s_barrier();
    }
  }

#pragma unroll
  for (int j = 0; j < 4; ++j) {
    int nb = n0 + wn + j * 16 + quad * 4;        // 4 consecutive n in regs
    float4 bv = *(const float4*)(bias + nb);
#pragma unroll
    for (int i = 0; i < 4; ++i) {
      int m = m0 + wm + i * 16 + l15;
      float4 ov;
      ov.x = acc[j][i][0] + bv.x;
      ov.y = acc[j][i][1] + bv.y;
      ov.z = acc[j][i][2] + bv.z;
      ov.w = acc[j][i][3] + bv.w;
      *(float4*)(C + m * 1024 + nb) = ov;
    }
  }
}

// ---------------- launch ----------------
extern "C" void kernel_launch(void* const* d_in, const int* in_sizes, int n_in,
                              void* d_out, int out_size, void* d_ws, size_t ws_size,
                              hipStream_t stream) {
  const float* x     = (const float*)d_in[0];
  const float* w_qkv = (const float*)d_in[1];
  const float* b_qkv = (const float*)d_in[2];
  const float* w_out = (const float*)d_in[3];
  const float* b_out = (const float*)d_in[4];
  float* out = (float*)d_out;
  char* ws = (char*)d_ws;

  unsigned short* wqkvb = (unsigned short*)(ws);              //  6 MB [3072][1024]
  unsigned short* woutb = (unsigned short*)(ws + 6291456);    //  2 MB [1024][1024]
  unsigned short* Qb    = (unsigned short*)(ws + 8388608);    // 16 MB [b,h,s,d] (x SL2E)
  unsigned short* Kb    = (unsigned short*)(ws + 25165824);   // 16 MB [b,h,s,d]
  unsigned short* Vtb   = (unsigned short*)(ws + 41943040);   // 16 MB [b,h,d,s]
  unsigned short* xb    = (unsigned short*)(ws + 58720256);   // 16 MB (reused as Ab)
  unsigned short* Ab    = xb;

  f32_to_bf16_all<<<12288, 256, 0, stream>>>(x, w_qkv, w_out, xb, wqkvb, woutb);
  gemm_qkv<<<dim3(32, 16), 512, 0, stream>>>(xb, wqkvb, b_qkv, Qb, Kb, Vtb);
  attn_k<<<512, 512, 0, stream>>>(Qb, Kb, Vtb, Ab);
  gemm_out<<<dim3(64, 8), 256, 0, stream>>>(Ab, woutb, b_out, out);
}

// Round 14
// 222.380 us; speedup vs baseline: 1.0941x; 1.0219x over previous
//
#include <hip/hip_runtime.h>

typedef __bf16 bf16x8 __attribute__((ext_vector_type(8)));
typedef float f32x4 __attribute__((ext_vector_type(4)));

#define SL2E 0.18033688011112042f  // log2(e)/8, folded into Q at gemm_qkv epilogue

__device__ __forceinline__ unsigned short f2bf(float f) {
  union { float f; unsigned u; } v; v.f = f;
  unsigned r = v.u + 0x7fffu + ((v.u >> 16) & 1u);
  return (unsigned short)(r >> 16);
}

__device__ __forceinline__ float fast_exp2(float x) {
#if __has_builtin(__builtin_amdgcn_exp2f)
  return __builtin_amdgcn_exp2f(x);
#else
  return exp2f(x);
#endif
}

__device__ __forceinline__ unsigned pack_bf2(float lo, float hi) {
  union { float f; unsigned u; } a, b;
  a.f = lo; b.f = hi;
#if __has_builtin(__builtin_amdgcn_perm)
  return __builtin_amdgcn_perm(b.u + 0x7fffu, a.u + 0x7fffu, 0x07060302u);
#else
  return ((b.u + 0x7fffu) & 0xffff0000u) | ((a.u + 0x7fffu) >> 16);
#endif
}

// async global->LDS, 16B/lane; HW dest = readfirstlane(lds base) + lane*16
__device__ __forceinline__ void gload16(const unsigned short* g, unsigned short* l) {
  __builtin_amdgcn_global_load_lds(
      (const __attribute__((address_space(1))) unsigned int*)g,
      (__attribute__((address_space(3))) unsigned int*)l, 16, 0, 0);
}

// swizzled chunk address (shorts): row R (64-short rows), colgroup cg of 8 shorts
#define SWZ(r, cg) ((((r) * 8) + ((cg) ^ ((r) & 7))) * 8)

// ---------------- fused fp32 -> bf16 conversion (x, w_qkv, w_out) ----------------
// grid-stride at 2048 blocks (G11): fewer dispatch slots + shorter tail.
__global__ __launch_bounds__(256) void f32_to_bf16_all(
    const float* __restrict__ x, const float* __restrict__ wq, const float* __restrict__ wo,
    unsigned short* __restrict__ xb, unsigned short* __restrict__ wqb, unsigned short* __restrict__ wob) {
  for (int i = blockIdx.x * 256 + threadIdx.x; i < 3145728; i += 2048 * 256) {
    const float* src; unsigned short* dst; int off;
    if (i < 2097152) { src = x; dst = xb; off = i; }
    else if (i < 2883584) { src = wq; dst = wqb; off = i - 2097152; }
    else { src = wo; dst = wob; off = i - 2883584; }
    float4 v = ((const float4*)src)[off];
    ushort4 o;
    o.x = f2bf(v.x); o.y = f2bf(v.y); o.z = f2bf(v.z); o.w = f2bf(v.w);
    ((ushort4*)dst)[off] = o;
  }
}

// ============ GEMM1: 256x192 block, BK=64, 8 waves of 64x96 (r8-measured: 62.0us) ============
// Best-measured gemm_qkv config (r8): LDS 112KB, 2-phase counted-vmcnt(7) dbuf.

template <bool SWAP>
__device__ __forceinline__ void tile_compute_6x4(
    const unsigned short* As_, const unsigned short* Bs_,
    int l15, int quad, int wm, int wn, f32x4* acc) {
#pragma unroll
  for (int kk = 0; kk < 2; ++kk) {
    int cg = kk * 4 + quad;
    bf16x8 af[4], bfr[6];
#pragma unroll
    for (int i = 0; i < 4; ++i) af[i] = *(const bf16x8*)(As_ + SWZ(wm + i * 16 + l15, cg));
#pragma unroll
    for (int j = 0; j < 6; ++j) bfr[j] = *(const bf16x8*)(Bs_ + SWZ(wn + j * 16 + l15, cg));
    if constexpr (SWAP) {
#pragma unroll
      for (int j = 0; j < 6; ++j)
#pragma unroll
        for (int i = 0; i < 4; ++i)
          acc[j * 4 + i] = __builtin_amdgcn_mfma_f32_16x16x32_bf16(bfr[j], af[i], acc[j * 4 + i], 0, 0, 0);
    } else {
#pragma unroll
      for (int i = 0; i < 4; ++i)
#pragma unroll
        for (int j = 0; j < 6; ++j)
          acc[i * 6 + j] = __builtin_amdgcn_mfma_f32_16x16x32_bf16(af[i], bfr[j], acc[i * 6 + j], 0, 0, 0);
    }
  }
}

template <bool SWAP>
__device__ __forceinline__ void mainloop_256x192(
    const unsigned short* const srcp[7], const int ldso[7],
    unsigned short* lds0, unsigned short* lds1,
    int l15, int quad, int wm, int wn, f32x4* acc) {
  // prologue: stage tile 0 -> buf0 (7 loads in flight per wave)
#pragma unroll
  for (int i = 0; i < 7; ++i) gload16(srcp[i], lds0 + ldso[i]);
#pragma unroll 1
  for (int t2 = 0; t2 < 16; t2 += 2) {
    // body A: stage t2+1 -> buf1; compute buf0
#pragma unroll
    for (int i = 0; i < 7; ++i) gload16(srcp[i] + (t2 + 1) * 64, lds1 + ldso[i]);
    asm volatile("s_waitcnt vmcnt(7)" ::: "memory");  // tile t2 landed; t2+1 in flight
    __builtin_amdgcn_s_barrier();
    __builtin_amdgcn_sched_barrier(0);
    tile_compute_6x4<SWAP>(lds0, lds0 + 16384, l15, quad, wm, wn, acc);
    __builtin_amdgcn_s_barrier();   // all waves done reading buf0 -> re-stageable
    // body B: stage t2+2 -> buf0; compute buf1
    if (t2 < 14) {
#pragma unroll
      for (int i = 0; i < 7; ++i) gload16(srcp[i] + (t2 + 2) * 64, lds0 + ldso[i]);
      asm volatile("s_waitcnt vmcnt(7)" ::: "memory");
    } else {
      asm volatile("s_waitcnt vmcnt(0)" ::: "memory");  // last tile: nothing younger
    }
    __builtin_amdgcn_s_barrier();
    __builtin_amdgcn_sched_barrier(0);
    tile_compute_6x4<SWAP>(lds1, lds1 + 16384, l15, quad, wm, wn, acc);
    __builtin_amdgcn_s_barrier();
  }
}

// ---------------- GEMM1: qkv = x @ w_qkv^T + b, scatter to Q/K/Vt ----------------
__global__ __launch_bounds__(512, 2) void gemm_qkv(
    const unsigned short* __restrict__ A,
    const unsigned short* __restrict__ Bt,
    const float* __restrict__ bias,
    unsigned short* __restrict__ Qb,
    unsigned short* __restrict__ Kb,
    unsigned short* __restrict__ Vtb) {
  const int K = 1024;
  // buf layout (shorts): [0,16384) = A tile 256x64; [16384, 28672) = B tile 192x64
  __shared__ unsigned short SMEM[2][28672];
  int tid = threadIdx.x;
  int w = tid >> 6, lane = tid & 63, l15 = lane & 15, quad = lane >> 4;
  int m0 = blockIdx.x * 256, n0 = blockIdx.y * 192;
  int wm = (w & 3) * 64, wn = (w >> 2) * 96;
  int b = m0 >> 12;

  // staging slots: 56 instrs (A rows q*8.., q<32; B rows (q-32)*8..), 7 per wave
  int rlane = lane >> 3;
  int cs = ((lane & 7) ^ rlane) * 8;  // inverse-swizzle source colgroup
  const unsigned short* srcp[7];
  int ldso[7];
#pragma unroll
  for (int i = 0; i < 7; ++i) {
    int q = w * 7 + i;
    if (q < 32) { srcp[i] = A + (m0 + q * 8 + rlane) * K + cs; ldso[i] = q * 512; }
    else { srcp[i] = Bt + (n0 + (q - 32) * 8 + rlane) * K + cs; ldso[i] = 16384 + (q - 32) * 512; }
  }

  f32x4 acc[24] = {};

  bool pureV = (n0 >= 2048);
  bool mixed = (n0 < 2048) && (n0 + 192 > 2048);   // n0 == 1920 only

  if (!pureV && !mixed) {
    // ---- Q/K blocks (incl. Q/K straddle at n0=960): swapped operands ----
    mainloop_256x192<true>(srcp, ldso, &SMEM[0][0], &SMEM[1][0], l15, quad, wm, wn, acc);
    int s_base = (m0 & 4095) + wm;
#pragma unroll
    for (int j = 0; j < 6; ++j) {
      int ng = n0 + wn + j * 16;                   // 16-aligned, never crosses 1024
      int t = ng >> 10;                            // 0=Q, 1=K (per-j)
      unsigned short* dst = t ? Kb : Qb;
      float sc = t ? 1.0f : SL2E;
      int h = (ng >> 6) & 15;
      int d0 = (ng & 63) + quad * 4;
      float4 bv = *(const float4*)(bias + ng + quad * 4);
      int head_base = (b * 16 + h) * 4096 * 64;
#pragma unroll
      for (int i = 0; i < 4; ++i) {
        int s = s_base + i * 16 + l15;
        f32x4 a = acc[j * 4 + i];
        ushort4 pk;
        pk.x = f2bf((a[0] + bv.x) * sc);
        pk.y = f2bf((a[1] + bv.y) * sc);
        pk.z = f2bf((a[2] + bv.z) * sc);
        pk.w = f2bf((a[3] + bv.w) * sc);
        *(ushort4*)(dst + head_base + s * 64 + d0) = pk;
      }
    }
  } else if (pureV) {
    // ---- pure V blocks: original orientation ----
    mainloop_256x192<false>(srcp, ldso, &SMEM[0][0], &SMEM[1][0], l15, quad, wm, wn, acc);
    int sblk = (m0 & 4095) + wm + quad * 4;
#pragma unroll
    for (int j = 0; j < 6; ++j) {
      int n_j = n0 + wn + j * 16 + l15;
      float bv = bias[n_j];
      int h = (n_j >> 6) & 15, d = n_j & 63;
      int vbase = ((b * 16 + h) * 64 + d) * 4096;
#pragma unroll
      for (int i = 0; i < 4; ++i) {
        int s = sblk + i * 16;
        f32x4 a = acc[i * 6 + j];
        ushort4 pk;
        pk.x = f2bf(a[0] + bv);
        pk.y = f2bf(a[1] + bv);
        pk.z = f2bf(a[2] + bv);
        pk.w = f2bf(a[3] + bv);
        *(ushort4*)(Vtb + vbase + s) = pk;
      }
    }
  } else {
    // ---- mixed K/V block (n0=1920): V orientation; per-j select V-vec / K-scalar ----
    mainloop_256x192<false>(srcp, ldso, &SMEM[0][0], &SMEM[1][0], l15, quad, wm, wn, acc);
#pragma unroll
    for (int j = 0; j < 6; ++j) {
      int ng = n0 + wn + j * 16;                   // wave-uniform per j
      if (ng >= 2048) {
        int n_j = ng + l15;
        float bv = bias[n_j];
        int h = (n_j >> 6) & 15, d = n_j & 63;
        int vbase = ((b * 16 + h) * 64 + d) * 4096;
        int sblk = (m0 & 4095) + wm + quad * 4;
#pragma unroll
        for (int i = 0; i < 4; ++i) {
          int s = sblk + i * 16;
          f32x4 a = acc[i * 6 + j];
          ushort4 pk;
          pk.x = f2bf(a[0] + bv);
          pk.y = f2bf(a[1] + bv);
          pk.z = f2bf(a[2] + bv);
          pk.w = f2bf(a[3] + bv);
          *(ushort4*)(Vtb + vbase + s) = pk;
        }
      } else {
        int n_j = ng + l15;
        float bv = bias[n_j];
        int h = (n_j >> 6) & 15, d = n_j & 63;
        int kbase = (b * 16 + h) * 4096 * 64 + d;
#pragma unroll
        for (int i = 0; i < 4; ++i) {
          f32x4 a = acc[i * 6 + j];
#pragma unroll
          for (int r = 0; r < 4; ++r) {
            int s = (m0 & 4095) + wm + i * 16 + quad * 4 + r;
            Kb[kbase + s * 64] = f2bf(a[r] + bv);
          }
        }
      }
    }
  }
}

// ---------------- fused block-diagonal attention ----------------
// r13-measured structure (8 waves x 32 q-rows, 512 thr, (512,4), 16 waves/CU)
// + ONE isolated delta: s_setprio(1/0) around QK and PV MFMA clusters (T5;
// m191 attn +4-7% with independent co-resident blocks -- r13 has 2 blocks/CU
// at different kt phases, exactly T5's role-diversity prerequisite).
#define LDP 72

__global__ __launch_bounds__(512, 4) void attn_k(
    const unsigned short* __restrict__ Qb,
    const unsigned short* __restrict__ Kb,
    const unsigned short* __restrict__ Vtb,
    unsigned short* __restrict__ Ab) {
  __shared__ unsigned short KV[2][2][4096];
  __shared__ unsigned short Ps[8][32 * LDP];   // per wave: 2 qb regions of 16*LDP

  int tid = threadIdx.x;
  int idx = blockIdx.x;
  // XCD-coherent decode: sharers of one K/V segment are idx, idx+8, idx+16,
  // idx+24 -> same XCD under round-robin dispatch (idx mod 8 fixed).
  int grp = ((idx >> 5) << 3) | (idx & 7);
  int qblk = (idx >> 3) & 3;
  int seg = grp & 3, h = (grp >> 2) & 15, b = grp >> 6;
  int w = tid >> 6, lane = tid & 63, l15 = lane & 15, quad = lane >> 4;
  int bh = b * 16 + h;
  int q0 = seg * 1024 + qblk * 256 + w * 32;

  const unsigned short* Kg = Kb + (bh * 4096 + seg * 1024) * 64;
  const unsigned short* Vg = Vtb + bh * 64 * 4096 + seg * 1024;

  int rlane = lane >> 3;
  int cs = ((lane & 7) ^ rlane) * 8;
  int srow = w * 8 + rlane;                     // this wave's staged chunk row

  const unsigned short* Qg = Qb + (bh * 4096 + q0) * 64;
  bf16x8 qf[2][2];
#pragma unroll
  for (int qb = 0; qb < 2; ++qb)
#pragma unroll
    for (int kk = 0; kk < 2; ++kk)
      qf[qb][kk] = *(const bf16x8*)(Qg + (qb * 16 + l15) * 64 + kk * 32 + quad * 8);

  f32x4 o[2][4] = {};
  float lsum[2] = {0.f, 0.f};
  unsigned short* Pw = Ps[w];

  // prologue: stage tile 0 (each wave: 1 K chunk + 1 V chunk)
  gload16(Kg + srow * 64 + cs, &KV[0][0][w * 512]);
  gload16(Vg + srow * 4096 + cs, &KV[0][1][w * 512]);

#pragma unroll 2
  for (int kt = 0; kt < 16; ++kt) {
    int cur = kt & 1;
    __syncthreads();
    if (kt < 15) {
      gload16(Kg + (kt + 1) * 4096 + srow * 64 + cs, &KV[cur ^ 1][0][w * 512]);
      gload16(Vg + (kt + 1) * 64 + srow * 4096 + cs, &KV[cur ^ 1][1][w * 512]);
    }
    const unsigned short* Kt = KV[cur][0];
    const unsigned short* Vt = KV[cur][1];

    uint2 pp[2][4];
#pragma unroll
    for (int half = 0; half < 2; ++half) {
      f32x4 st[2][2] = {};
#pragma unroll
      for (int kk = 0; kk < 2; ++kk) {
        int cg = kk * 4 + quad;
        bf16x8 kf0 = *(const bf16x8*)(Kt + SWZ(half * 32 + l15, cg));
        bf16x8 kf1 = *(const bf16x8*)(Kt + SWZ(half * 32 + 16 + l15, cg));
        __builtin_amdgcn_s_setprio(1);
#pragma unroll
        for (int qb = 0; qb < 2; ++qb) {
          st[0][qb] = __builtin_amdgcn_mfma_f32_16x16x32_bf16(kf0, qf[qb][kk], st[0][qb], 0, 0, 0);
          st[1][qb] = __builtin_amdgcn_mfma_f32_16x16x32_bf16(kf1, qf[qb][kk], st[1][qb], 0, 0, 0);
        }
        __builtin_amdgcn_s_setprio(0);
      }
#pragma unroll
      for (int kb = 0; kb < 2; ++kb)
#pragma unroll
        for (int qb = 0; qb < 2; ++qb) {
          f32x4 s = st[kb][qb];
          float p0 = fast_exp2(s[0]), p1 = fast_exp2(s[1]);
          float p2 = fast_exp2(s[2]), p3 = fast_exp2(s[3]);
          lsum[qb] += (p0 + p1) + (p2 + p3);
          uint2 d;
          d.x = pack_bf2(p0, p1);
          d.y = pack_bf2(p2, p3);
          pp[qb][half * 2 + kb] = d;
        }
    }

    // write P for both qb (disjoint regions) before any consumer ds_read
#pragma unroll
    for (int qb = 0; qb < 2; ++qb)
#pragma unroll
      for (int g = 0; g < 4; ++g)
        *(uint2*)(Pw + qb * 16 * LDP + l15 * LDP + g * 16 + quad * 4) = pp[qb][g];

#pragma unroll
    for (int kk = 0; kk < 2; ++kk) {
      bf16x8 vfk[4];
#pragma unroll
      for (int db = 0; db < 4; ++db)
        vfk[db] = *(const bf16x8*)(Vt + SWZ(db * 16 + l15, kk * 4 + quad));
#pragma unroll
      for (int qb = 0; qb < 2; ++qb) {
        bf16x8 pa = *(const bf16x8*)(Pw + qb * 16 * LDP + l15 * LDP + kk * 32 + quad * 8);
        __builtin_amdgcn_s_setprio(1);
#pragma unroll
        for (int db = 0; db < 4; ++db)
          o[qb][db] = __builtin_amdgcn_mfma_f32_16x16x32_bf16(pa, vfk[db], o[qb][db], 0, 0, 0);
        __builtin_amdgcn_s_setprio(0);
      }
    }
  }

#pragma unroll
  for (int qb = 0; qb < 2; ++qb) {
    lsum[qb] += __shfl_xor(lsum[qb], 16);
    lsum[qb] += __shfl_xor(lsum[qb], 32);
  }

  // all waves must be done reading KV before reusing the full 32KB as scratch
  __syncthreads();
  float* Wf = (float*)(&KV[0][0][0]) + w * 1024;
#pragma unroll
  for (int qb = 0; qb < 2; ++qb) {
#pragma unroll
    for (int db = 0; db < 4; ++db)
#pragma unroll
      for (int r = 0; r < 4; ++r)
        Wf[(quad * 4 + r) * 64 + db * 16 + l15] = o[qb][db][r];
    float inv = 1.0f / lsum[qb];
    float4 x0 = *(float4*)(Wf + l15 * 64 + quad * 8);
    float4 x1 = *(float4*)(Wf + l15 * 64 + quad * 8 + 4);
    float4 x2 = *(float4*)(Wf + l15 * 64 + (quad + 4) * 8);
    float4 x3 = *(float4*)(Wf + l15 * 64 + (quad + 4) * 8 + 4);
    uint4 u0, u1;
    u0.x = pack_bf2(x0.x * inv, x0.y * inv);
    u0.y = pack_bf2(x0.z * inv, x0.w * inv);
    u0.z = pack_bf2(x1.x * inv, x1.y * inv);
    u0.w = pack_bf2(x1.z * inv, x1.w * inv);
    u1.x = pack_bf2(x2.x * inv, x2.y * inv);
    u1.y = pack_bf2(x2.z * inv, x2.w * inv);
    u1.z = pack_bf2(x3.x * inv, x3.y * inv);
    u1.w = pack_bf2(x3.z * inv, x3.w * inv);
    int sg = q0 + qb * 16 + l15;
    int base = (b * 4096 + sg) * 1024 + h * 64;
    *(uint4*)(Ab + base + quad * 8) = u0;
    *(uint4*)(Ab + base + (quad + 4) * 8) = u1;
  }
}

// ---------------- GEMM2: out = Ab @ w_out^T + b_out (fp32 out), BK=64 ----------------
// Swapped operands: lane owns (m=l15, 4 consecutive n) -> float4 stores along n.
__global__ __launch_bounds__(256) void gemm_out(
    const unsigned short* __restrict__ A,
    const unsigned short* __restrict__ Bt,
    const float* __restrict__ bias,
    float* __restrict__ C) {
  const int K = 1024;
  __shared__ unsigned short As2[2][8192];
  __shared__ unsigned short Bs2[2][8192];
  int tid = threadIdx.x;
  int m0 = blockIdx.x * 128, n0 = blockIdx.y * 128;
  int w = tid >> 6, lane = tid & 63, l15 = lane & 15, quad = lane >> 4;
  int wm = (w & 1) * 64, wn = (w >> 1) * 64;

  f32x4 acc[4][4] = {};

  int rs = w * 32 + (lane >> 3);
  int cs = ((lane & 7) ^ (lane >> 3)) * 8;
  const unsigned short* Ag = A + (m0 + rs) * K + cs;
  const unsigned short* Bg = Bt + (n0 + rs) * K + cs;

  // prologue: stage tile 0 -> buf0
#pragma unroll
  for (int i = 0; i < 4; ++i) {
    gload16(Ag + i * 8 * K, &As2[0][0] + w * 2048 + i * 512);
    gload16(Bg + i * 8 * K, &Bs2[0][0] + w * 2048 + i * 512);
  }
#pragma unroll 1
  for (int kt2 = 0; kt2 < 16; kt2 += 2) {
#pragma unroll
    for (int half = 0; half < 2; ++half) {
      int kt = kt2 + half;
      unsigned short* Awr = half ? &As2[0][0] : &As2[1][0];
      unsigned short* Bwr = half ? &Bs2[0][0] : &Bs2[1][0];
      const unsigned short* Ard = half ? &As2[1][0] : &As2[0][0];
      const unsigned short* Brd = half ? &Bs2[1][0] : &Bs2[0][0];
      if (kt < 15) {
#pragma unroll
        for (int i = 0; i < 4; ++i) {
          gload16(Ag + i * 8 * K + (kt + 1) * 64, Awr + w * 2048 + i * 512);
          gload16(Bg + i * 8 * K + (kt + 1) * 64, Bwr + w * 2048 + i * 512);
        }
        asm volatile("s_waitcnt vmcnt(8)" ::: "memory");
      } else {
        asm volatile("s_waitcnt vmcnt(0)" ::: "memory");
      }
      __builtin_amdgcn_s_barrier();
      __builtin_amdgcn_sched_barrier(0);
#pragma unroll
      for (int kk = 0; kk < 2; ++kk) {
        int swk = (((kk * 4 + quad) ^ (l15 & 7))) * 8;
        bf16x8 af[4], bfr[4];
#pragma unroll
        for (int i = 0; i < 4; ++i) af[i] = *(const bf16x8*)(Ard + (wm + i * 16 + l15) * 64 + swk);
#pragma unroll
        for (int j = 0; j < 4; ++j) bfr[j] = *(const bf16x8*)(Brd + (wn + j * 16 + l15) * 64 + swk);
#pragma unroll
        for (int j = 0; j < 4; ++j)
#pragma unroll
          for (int i = 0; i < 4; ++i)
            acc[j][i] = __builtin_amdgcn_mfma_f32_16x16x32_bf16(bfr[j], af[i], acc[j][i], 0, 0, 0);
      }
      __builtin_amdgcn_s_barrier();
    }
  }

#pragma unroll
  for (int j = 0; j < 4; ++j) {
    int nb = n0 + wn + j * 16 + quad * 4;        // 4 consecutive n in regs
    float4 bv = *(const float4*)(bias + nb);
#pragma unroll
    for (int i = 0; i < 4; ++i) {
      int m = m0 + wm + i * 16 + l15;
      float4 ov;
      ov.x = acc[j][i][0] + bv.x;
      ov.y = acc[j][i][1] + bv.y;
      ov.z = acc[j][i][2] + bv.z;
      ov.w = acc[j][i][3] + bv.w;
      *(float4*)(C + m * 1024 + nb) = ov;
    }
  }
}

// ---------------- launch ----------------
extern "C" void kernel_launch(void* const* d_in, const int* in_sizes, int n_in,
                              void* d_out, int out_size, void* d_ws, size_t ws_size,
                              hipStream_t stream) {
  const float* x     = (const float*)d_in[0];
  const float* w_qkv = (const float*)d_in[1];
  const float* b_qkv = (const float*)d_in[2];
  const float* w_out = (const float*)d_in[3];
  const float* b_out = (const float*)d_in[4];
  float* out = (float*)d_out;
  char* ws = (char*)d_ws;

  unsigned short* wqkvb = (unsigned short*)(ws);              //  6 MB [3072][1024]
  unsigned short* woutb = (unsigned short*)(ws + 6291456);    //  2 MB [1024][1024]
  unsigned short* Qb    = (unsigned short*)(ws + 8388608);    // 16 MB [b,h,s,d] (x SL2E)
  unsigned short* Kb    = (unsigned short*)(ws + 25165824);   // 16 MB [b,h,s,d]
  unsigned short* Vtb   = (unsigned short*)(ws + 41943040);   // 16 MB [b,h,d,s]
  unsigned short* xb    = (unsigned short*)(ws + 58720256);   // 16 MB (reused as Ab)
  unsigned short* Ab    = xb;

  f32_to_bf16_all<<<2048, 256, 0, stream>>>(x, w_qkv, w_out, xb, wqkvb, woutb);
  gemm_qkv<<<dim3(32, 16), 512, 0, stream>>>(xb, wqkvb, b_qkv, Qb, Kb, Vtb);
  attn_k<<<512, 512, 0, stream>>>(Qb, Kb, Vtb, Ab);
  gemm_out<<<dim3(64, 8), 256, 0, stream>>>(Ab, woutb, b_out, out);
}